// Round 9
// baseline (121.921 us; speedup 1.0000x reference)
//
#include <hip/hip_runtime.h>
#include <cstdint>
#include <cstddef>

#define BATCH 4
#define CIN   512
#define NPIX  1024
#define HEADS 16
#define DH    32
#define DATTN 512
#define O_QKV 1536

typedef unsigned short u16;
typedef __bf16 bf16x4 __attribute__((ext_vector_type(4)));
typedef __bf16 bf16x8 __attribute__((ext_vector_type(8)));
typedef float  f32x4  __attribute__((ext_vector_type(4)));

typedef const __attribute__((address_space(1))) void g1_t;
typedef __attribute__((address_space(3))) void l3_t;

#if defined(__has_builtin)
#if __has_builtin(__builtin_amdgcn_exp2f)
#define EXP2(x) __builtin_amdgcn_exp2f(x)
#endif
#endif
#ifndef EXP2
#define EXP2(x) __expf((x) * 0.6931471805599453f)
#endif

__device__ __forceinline__ u16 f2bf(float f) {
  unsigned u = __float_as_uint(f);
  u += 0x7fffu + ((u >> 16) & 1u);
  return (u16)(u >> 16);
}

// async global->LDS, 16B per lane; lp must be wave-uniform (HW: base + lane*16)
__device__ __forceinline__ void gl_lds16(const void* gp, void* lp) {
  __builtin_amdgcn_global_load_lds((g1_t*)gp, (l3_t*)lp, 16, 0, 0);
}

// ---------------------------------------------------------------------------
// prep_w: convert w_qkv [1536][512] and w_proj [512][512] f32 -> bf16.
// ---------------------------------------------------------------------------
__global__ __launch_bounds__(256) void prep_w(const float* __restrict__ w1,
                                              const float* __restrict__ w2,
                                              u16* __restrict__ o1,
                                              u16* __restrict__ o2) {
  const int idx = blockIdx.x * 256 + threadIdx.x;   // float4 index
  const int n1 = (O_QKV * CIN) >> 2;                // 196608
  float4 v = (idx < n1) ? reinterpret_cast<const float4*>(w1)[idx]
                        : reinterpret_cast<const float4*>(w2)[idx - n1];
  uint2 pk = make_uint2((unsigned)f2bf(v.x) | ((unsigned)f2bf(v.y) << 16),
                        (unsigned)f2bf(v.z) | ((unsigned)f2bf(v.w) << 16));
  if (idx < n1) reinterpret_cast<uint2*>(o1)[idx] = pk;
  else          reinterpret_cast<uint2*>(o2)[idx - n1] = pk;
}

// ---------------------------------------------------------------------------
// prep_x: x [B][C][N] f32 -> xt [B][N][C] bf16 (tiled 64x64 LDS transpose)
// ---------------------------------------------------------------------------
__global__ __launch_bounds__(256) void prep_x(const float* __restrict__ x,
                                              u16* __restrict__ xt) {
  __shared__ float sT[64][65];
  const int t  = threadIdx.x;
  const int n0 = blockIdx.x * 64;
  const int c0 = blockIdx.y * 64;
  const int b  = blockIdx.z;
  const float* xb = x + ((size_t)b * CIN + c0) * NPIX + n0;
#pragma unroll
  for (int i = 0; i < 4; ++i) {
    int r   = i * 16 + (t >> 4);
    int col = (t & 15) << 2;
    float4 v = *reinterpret_cast<const float4*>(&xb[(size_t)r * NPIX + col]);
    sT[r][col + 0] = v.x; sT[r][col + 1] = v.y;
    sT[r][col + 2] = v.z; sT[r][col + 3] = v.w;
  }
  __syncthreads();
#pragma unroll
  for (int i = 0; i < 2; ++i) {
    int nl = t >> 2;
    int ch = (t & 3) + (i << 2);
    u16 tmp[8];
#pragma unroll
    for (int e = 0; e < 8; ++e) tmp[e] = f2bf(sT[(ch << 3) + e][nl]);
    *reinterpret_cast<uint4*>(&xt[((size_t)b * NPIX + n0 + nl) * CIN + c0 + (ch << 3)]) =
        *reinterpret_cast<uint4*>(tmp);
  }
}

// ---------------------------------------------------------------------------
// QKV GEMM (MFMA): M-tile=96 (one head), N-tile=128, BK=64, 4 waves.
// Epilogue: +bias, bf16; q PRE-SCALED by scale*log2e (attn uses exp2 domain).
// qt/kt [b][h][n][32], vt [b][h][d][n].
// ---------------------------------------------------------------------------
__global__ __launch_bounds__(256) void gemm_qkv_mfma(const u16* __restrict__ wq,
                                                     const u16* __restrict__ xt,
                                                     const float* __restrict__ bias,
                                                     u16* __restrict__ qt,
                                                     u16* __restrict__ kt,
                                                     u16* __restrict__ vt) {
  __shared__ __align__(16) u16 sA[96 * 64];
  __shared__ __align__(16) u16 sB[128 * 64];
  const int t  = threadIdx.x;
  const int w  = t >> 6, l = t & 63, g = l >> 4, ln = l & 15;
  const int n0 = blockIdx.x * 128;
  const int h  = blockIdx.y;
  const int b  = blockIdx.z;
  const int wm = w >> 1, wn = w & 1;

  const u16* wbase = wq + (size_t)h * 96 * CIN;
  const u16* xbase = xt + ((size_t)b * NPIX + n0) * CIN;

  f32x4 acc[3][4];
#pragma unroll
  for (int mi = 0; mi < 3; ++mi)
#pragma unroll
    for (int ni = 0; ni < 4; ++ni) acc[mi][ni] = {0.f, 0.f, 0.f, 0.f};

  for (int k0 = 0; k0 < CIN; k0 += 64) {
#pragma unroll
    for (int i = 0; i < 3; ++i) {
      int chunk = i * 256 + (w << 6) + l;
      gl_lds16(wbase + ((size_t)(chunk >> 3)) * CIN + k0 + ((chunk & 7) << 3),
               (char*)sA + i * 4096 + (w << 10));
    }
#pragma unroll
    for (int i = 0; i < 4; ++i) {
      int chunk = i * 256 + (w << 6) + l;
      gl_lds16(xbase + ((size_t)(chunk >> 3)) * CIN + k0 + ((chunk & 7) << 3),
               (char*)sB + i * 4096 + (w << 10));
    }
    __syncthreads();
#pragma unroll
    for (int kk = 0; kk < 64; kk += 32) {
      bf16x8 af[3], bfr[4];
#pragma unroll
      for (int mi = 0; mi < 3; ++mi)
        af[mi] = *reinterpret_cast<const bf16x8*>(&sA[(48 * wm + 16 * mi + ln) * 64 + kk + (g << 3)]);
#pragma unroll
      for (int ni = 0; ni < 4; ++ni)
        bfr[ni] = *reinterpret_cast<const bf16x8*>(&sB[((wn << 6) + (ni << 4) + ln) * 64 + kk + (g << 3)]);
#pragma unroll
      for (int mi = 0; mi < 3; ++mi)
#pragma unroll
        for (int ni = 0; ni < 4; ++ni)
          acc[mi][ni] = __builtin_amdgcn_mfma_f32_16x16x32_bf16(af[mi], bfr[ni], acc[mi][ni], 0, 0, 0);
    }
    __syncthreads();
  }

  const float QSC = 0.17677669529663687f * 1.4426950408889634f;  // scale*log2e
  const float* bh = bias + h * 96;
#pragma unroll
  for (int mi = 0; mi < 3; ++mi) {
    const int sec = 48 * wm + 16 * mi;
    const int rb  = sec + (g << 2);
    const float b0 = bh[rb + 0], b1 = bh[rb + 1], b2 = bh[rb + 2], b3 = bh[rb + 3];
#pragma unroll
    for (int ni = 0; ni < 4; ++ni) {
      const int n = n0 + (wn << 6) + (ni << 4) + ln;
      f32x4 a = acc[mi][ni];
      float v0 = a[0] + b0, v1 = a[1] + b1, v2 = a[2] + b2, v3 = a[3] + b3;
      if (sec < 32) { v0 *= QSC; v1 *= QSC; v2 *= QSC; v3 *= QSC; }
      u16 e0 = f2bf(v0), e1 = f2bf(v1), e2 = f2bf(v2), e3 = f2bf(v3);
      if (sec < 32) {
        const int d = sec + (g << 2);
        uint2 pk = make_uint2((unsigned)e0 | ((unsigned)e1 << 16),
                              (unsigned)e2 | ((unsigned)e3 << 16));
        *reinterpret_cast<uint2*>(&qt[(((size_t)(b * HEADS + h)) * NPIX + n) * DH + d]) = pk;
      } else if (sec < 64) {
        const int d = sec - 32 + (g << 2);
        uint2 pk = make_uint2((unsigned)e0 | ((unsigned)e1 << 16),
                              (unsigned)e2 | ((unsigned)e3 << 16));
        *reinterpret_cast<uint2*>(&kt[(((size_t)(b * HEADS + h)) * NPIX + n) * DH + d]) = pk;
      } else {
        const int d = sec - 64 + (g << 2);
        u16* vp = &vt[(((size_t)(b * HEADS + h)) * DH + d) * NPIX + n];
        vp[0] = e0; vp[NPIX] = e1; vp[2 * NPIX] = e2; vp[3 * NPIX] = e3;
      }
    }
  }
}

// ---------------------------------------------------------------------------
// MFMA flash attention v9 -- BARRIER-FREE.
// Each wave = independent flash attn over (b, h, 16 i-rows). No K/V LDS:
// fragments load straight global->VGPR (coalesced 16B/lane from kt [n][32]
// and vt [d][n]; K/V working set 1MB/XCD -> L2-resident). rel double-buffered
// in NAMED reg sets (2-step unrolled body -- no runtime-indexed arrays).
// P transpose via per-wave-private LDS (2KB/wave, lgkmcnt-ordered, no barrier).
// Grid 1024 x 256thr: xcd=bid&7, sl=bid>>3; b=sl&3 (siblings dist-8 -> same
// XCD, adjacent -> rel L2/L3 reuse), i0=((sl>>2)&15)<<6, h=(xcd<<1)|(sl>>6).
// ---------------------------------------------------------------------------
__global__ __launch_bounds__(256, 4) void attn_mfma(const u16* __restrict__ qt,
                                                    const u16* __restrict__ kt,
                                                    const u16* __restrict__ vt,
                                                    const float* __restrict__ rel,
                                                    u16* __restrict__ aout) {
  __shared__ __align__(16) u16 sP[4][1024];      // per-wave [16][8slot][8], swizzled

  const int t  = threadIdx.x;
  const int w  = t >> 6, l = t & 63, g = l >> 4, ln = l & 15;
  const int bid = blockIdx.x;
  const int xcd = bid & 7, sl = bid >> 3;   // sl 0..127
  const int b   = sl & 3;
  const int i0  = ((sl >> 2) & 15) << 6;
  const int h   = (xcd << 1) | (sl >> 6);
  const int iw  = w;                        // i-segment (16 rows)

  const size_t bh = (size_t)(b * HEADS + h);

  // per-lane fragment bases
  // K frag jj: lane reads kt row j = 4*ln + jj, bytes [8g..8g+7] (bf16)
  const u16* kbase = kt + (bh * NPIX + (ln << 2)) * DH + (g << 3);
  // V frag (kc,dc): lane reads vt row d = 16*dc + ln, cols s*64+32*kc+8g..
  const u16* vbase0 = vt + (bh * DH + ln) * NPIX + (g << 3);
  const u16* vbase1 = vbase0 + 16 * NPIX;
  // rel: rows i0+16*iw+4g+v, cols s*64 + 4*ln + (0..3)
  const float* relp = rel + ((size_t)h * NPIX + i0 + (iw << 4) + (g << 2)) * NPIX +
                      (ln << 2);

  // Q fragment (pre-scaled by scale*log2e)
  bf16x8 qf = *reinterpret_cast<const bf16x8*>(
      qt + (bh * NPIX + i0 + (iw << 4) + ln) * DH + (g << 3));

  f32x4 vzero = {0.f, 0.f, 0.f, 0.f};
  f32x4 accO[2] = {vzero, vzero};
  f32x4 l_lane = vzero;

  u16* sPw = &sP[w][0];
  const float LOG2E = 1.4426950408889634f;

  // rel prologue (step 0) into set A
  f32x4 ra0 = *reinterpret_cast<const f32x4*>(relp);
  f32x4 ra1 = *reinterpret_cast<const f32x4*>(relp + NPIX);
  f32x4 ra2 = *reinterpret_cast<const f32x4*>(relp + 2 * NPIX);
  f32x4 ra3 = *reinterpret_cast<const f32x4*>(relp + 3 * NPIX);
  f32x4 rb0 = vzero, rb1 = vzero, rb2 = vzero, rb3 = vzero;

#define STEP(s_, R0, R1, R2, R3, RN0, RN1, RN2, RN3)                          \
  do {                                                                         \
    const int s = (s_);                                                        \
    /* K frags for this step (first use ~after V/rel issue) */                 \
    const u16* kp = kbase + (size_t)s * 2048;                                  \
    bf16x8 kf0 = *reinterpret_cast<const bf16x8*>(kp);                         \
    bf16x8 kf1 = *reinterpret_cast<const bf16x8*>(kp + 32);                    \
    bf16x8 kf2 = *reinterpret_cast<const bf16x8*>(kp + 64);                    \
    bf16x8 kf3 = *reinterpret_cast<const bf16x8*>(kp + 96);                    \
    /* V frags for this step (used after softmax) */                           \
    const u16* vp0 = vbase0 + (size_t)s * 64;                                  \
    const u16* vp1 = vbase1 + (size_t)s * 64;                                  \
    bf16x8 vf00 = *reinterpret_cast<const bf16x8*>(vp0);                       \
    bf16x8 vf10 = *reinterpret_cast<const bf16x8*>(vp0 + 32);                  \
    bf16x8 vf01 = *reinterpret_cast<const bf16x8*>(vp1);                       \
    bf16x8 vf11 = *reinterpret_cast<const bf16x8*>(vp1 + 32);                  \
    /* rel prefetch for s+1 into the other named set */                        \
    if (s < 15) {                                                              \
      const float* rn = relp + (size_t)(s + 1) * 64;                           \
      RN0 = *reinterpret_cast<const f32x4*>(rn);                               \
      RN1 = *reinterpret_cast<const f32x4*>(rn + NPIX);                        \
      RN2 = *reinterpret_cast<const f32x4*>(rn + 2 * NPIX);                    \
      RN3 = *reinterpret_cast<const f32x4*>(rn + 3 * NPIX);                    \
    }                                                                          \
    /* S' = Q'^T K: fragment jj covers cols j = 4*ln + jj */                   \
    f32x4 sfr0, sfr1, sfr2, sfr3;                                              \
    __builtin_amdgcn_s_setprio(1);                                             \
    sfr0 = __builtin_amdgcn_mfma_f32_16x16x32_bf16(qf, kf0, vzero, 0, 0, 0);   \
    sfr1 = __builtin_amdgcn_mfma_f32_16x16x32_bf16(qf, kf1, vzero, 0, 0, 0);   \
    sfr2 = __builtin_amdgcn_mfma_f32_16x16x32_bf16(qf, kf2, vzero, 0, 0, 0);   \
    sfr3 = __builtin_amdgcn_mfma_f32_16x16x32_bf16(qf, kf3, vzero, 0, 0, 0);   \
    __builtin_amdgcn_s_setprio(0);                                             \
    /* P = exp2(S' + rel*log2e); swizzled b64 write per row */                 \
    _Pragma("unroll")                                                          \
    for (int v = 0; v < 4; ++v) {                                              \
      float p0 = EXP2(fmaf(R0[v], LOG2E, sfr0[v]));                            \
      float p1 = EXP2(fmaf(R1[v], LOG2E, sfr1[v]));                            \
      float p2 = EXP2(fmaf(R2[v], LOG2E, sfr2[v]));                            \
      float p3 = EXP2(fmaf(R3[v], LOG2E, sfr3[v]));                            \
      /* careful: R_k[v] is rel for row v, col 4ln+k  */                       \
      l_lane[v] += (p0 + p1) + (p2 + p3);                                      \
      bf16x4 pk;                                                               \
      pk[0] = (__bf16)p0; pk[1] = (__bf16)p1;                                  \
      pk[2] = (__bf16)p2; pk[3] = (__bf16)p3;                                  \
      const int rw = (g << 2) + v;                                             \
      *reinterpret_cast<bf16x4*>(                                              \
          sPw + rw * 64 + ((((ln >> 1) ^ (rw & 7)) << 3) | ((ln & 1) << 2))) = pk; \
    }                                                                          \
    /* PV: acc[i][d] += P[i,j] * V[d,j] */                                     \
    __builtin_amdgcn_s_setprio(1);                                             \
    {                                                                          \
      bf16x8 pa0 = *reinterpret_cast<const bf16x8*>(sPw + ln * 64 + ((g ^ (ln & 7)) << 3)); \
      accO[0] = __builtin_amdgcn_mfma_f32_16x16x32_bf16(pa0, vf00, accO[0], 0, 0, 0); \
      accO[1] = __builtin_amdgcn_mfma_f32_16x16x32_bf16(pa0, vf01, accO[1], 0, 0, 0); \
      bf16x8 pa1 = *reinterpret_cast<const bf16x8*>(sPw + ln * 64 + (((4 | g) ^ (ln & 7)) << 3)); \
      accO[0] = __builtin_amdgcn_mfma_f32_16x16x32_bf16(pa1, vf10, accO[0], 0, 0, 0); \
      accO[1] = __builtin_amdgcn_mfma_f32_16x16x32_bf16(pa1, vf11, accO[1], 0, 0, 0); \
    }                                                                          \
    __builtin_amdgcn_s_setprio(0);                                             \
  } while (0)

  // wait: rel layout note -- R_jj[v] must be rel[row 4g+v][col 4ln+jj]:
  // ra_v loaded as f32x4 over cols is [row fixed]. We loaded ra0..ra3 as ROWS
  // (v index), each f32x4 over 4 cols (jj). So exp arg for (jj, v) is
  // R_v[jj], not R_jj[v]. The STEP macro above is written with R0..R3 = rows,
  // indexed [v] -- that would be wrong. Fixed by passing rows and indexing
  // [jj] per row inside: see corrected usage below (R0=row0 etc., and the
  // exp lines use R(v)[jj]). To keep the macro simple we index rows by v:
  //   p_jj = exp2(fma(Rv[jj], log2e, sfr_jj[v]))  -- implemented correctly:
#undef STEP
#define STEP(s_, R0, R1, R2, R3, RN0, RN1, RN2, RN3)                          \
  do {                                                                         \
    const int s = (s_);                                                        \
    const u16* kp = kbase + (size_t)s * 2048;                                  \
    bf16x8 kf0 = *reinterpret_cast<const bf16x8*>(kp);                         \
    bf16x8 kf1 = *reinterpret_cast<const bf16x8*>(kp + 32);                    \
    bf16x8 kf2 = *reinterpret_cast<const bf16x8*>(kp + 64);                    \
    bf16x8 kf3 = *reinterpret_cast<const bf16x8*>(kp + 96);                    \
    const u16* vp0 = vbase0 + (size_t)s * 64;                                  \
    const u16* vp1 = vbase1 + (size_t)s * 64;                                  \
    bf16x8 vf00 = *reinterpret_cast<const bf16x8*>(vp0);                       \
    bf16x8 vf10 = *reinterpret_cast<const bf16x8*>(vp0 + 32);                  \
    bf16x8 vf01 = *reinterpret_cast<const bf16x8*>(vp1);                       \
    bf16x8 vf11 = *reinterpret_cast<const bf16x8*>(vp1 + 32);                  \
    if (s < 15) {                                                              \
      const float* rn = relp + (size_t)(s + 1) * 64;                           \
      RN0 = *reinterpret_cast<const f32x4*>(rn);                               \
      RN1 = *reinterpret_cast<const f32x4*>(rn + NPIX);                        \
      RN2 = *reinterpret_cast<const f32x4*>(rn + 2 * NPIX);                    \
      RN3 = *reinterpret_cast<const f32x4*>(rn + 3 * NPIX);                    \
    }                                                                          \
    f32x4 sfr0, sfr1, sfr2, sfr3;                                              \
    __builtin_amdgcn_s_setprio(1);                                             \
    sfr0 = __builtin_amdgcn_mfma_f32_16x16x32_bf16(qf, kf0, vzero, 0, 0, 0);   \
    sfr1 = __builtin_amdgcn_mfma_f32_16x16x32_bf16(qf, kf1, vzero, 0, 0, 0);   \
    sfr2 = __builtin_amdgcn_mfma_f32_16x16x32_bf16(qf, kf2, vzero, 0, 0, 0);   \
    sfr3 = __builtin_amdgcn_mfma_f32_16x16x32_bf16(qf, kf3, vzero, 0, 0, 0);   \
    __builtin_amdgcn_s_setprio(0);                                             \
    {                                                                          \
      float p0, p1, p2, p3; bf16x4 pk; int rw;                                 \
      p0 = EXP2(fmaf(R0[0], LOG2E, sfr0[0]));                                  \
      p1 = EXP2(fmaf(R0[1], LOG2E, sfr1[0]));                                  \
      p2 = EXP2(fmaf(R0[2], LOG2E, sfr2[0]));                                  \
      p3 = EXP2(fmaf(R0[3], LOG2E, sfr3[0]));                                  \
      l_lane[0] += (p0 + p1) + (p2 + p3);                                      \
      pk[0] = (__bf16)p0; pk[1] = (__bf16)p1; pk[2] = (__bf16)p2; pk[3] = (__bf16)p3; \
      rw = (g << 2) + 0;                                                       \
      *reinterpret_cast<bf16x4*>(sPw + rw * 64 + ((((ln >> 1) ^ (rw & 7)) << 3) | ((ln & 1) << 2))) = pk; \
      p0 = EXP2(fmaf(R1[0], LOG2E, sfr0[1]));                                  \
      p1 = EXP2(fmaf(R1[1], LOG2E, sfr1[1]));                                  \
      p2 = EXP2(fmaf(R1[2], LOG2E, sfr2[1]));                                  \
      p3 = EXP2(fmaf(R1[3], LOG2E, sfr3[1]));                                  \
      l_lane[1] += (p0 + p1) + (p2 + p3);                                      \
      pk[0] = (__bf16)p0; pk[1] = (__bf16)p1; pk[2] = (__bf16)p2; pk[3] = (__bf16)p3; \
      rw = (g << 2) + 1;                                                       \
      *reinterpret_cast<bf16x4*>(sPw + rw * 64 + ((((ln >> 1) ^ (rw & 7)) << 3) | ((ln & 1) << 2))) = pk; \
      p0 = EXP2(fmaf(R2[0], LOG2E, sfr0[2]));                                  \
      p1 = EXP2(fmaf(R2[1], LOG2E, sfr1[2]));                                  \
      p2 = EXP2(fmaf(R2[2], LOG2E, sfr2[2]));                                  \
      p3 = EXP2(fmaf(R2[3], LOG2E, sfr3[2]));                                  \
      l_lane[2] += (p0 + p1) + (p2 + p3);                                      \
      pk[0] = (__bf16)p0; pk[1] = (__bf16)p1; pk[2] = (__bf16)p2; pk[3] = (__bf16)p3; \
      rw = (g << 2) + 2;                                                       \
      *reinterpret_cast<bf16x4*>(sPw + rw * 64 + ((((ln >> 1) ^ (rw & 7)) << 3) | ((ln & 1) << 2))) = pk; \
      p0 = EXP2(fmaf(R3[0], LOG2E, sfr0[3]));                                  \
      p1 = EXP2(fmaf(R3[1], LOG2E, sfr1[3]));                                  \
      p2 = EXP2(fmaf(R3[2], LOG2E, sfr2[3]));                                  \
      p3 = EXP2(fmaf(R3[3], LOG2E, sfr3[3]));                                  \
      l_lane[3] += (p0 + p1) + (p2 + p3);                                      \
      pk[0] = (__bf16)p0; pk[1] = (__bf16)p1; pk[2] = (__bf16)p2; pk[3] = (__bf16)p3; \
      rw = (g << 2) + 3;                                                       \
      *reinterpret_cast<bf16x4*>(sPw + rw * 64 + ((((ln >> 1) ^ (rw & 7)) << 3) | ((ln & 1) << 2))) = pk; \
    }                                                                          \
    __builtin_amdgcn_s_setprio(1);                                             \
    {                                                                          \
      bf16x8 pa0 = *reinterpret_cast<const bf16x8*>(sPw + ln * 64 + ((g ^ (ln & 7)) << 3)); \
      accO[0] = __builtin_amdgcn_mfma_f32_16x16x32_bf16(pa0, vf00, accO[0], 0, 0, 0); \
      accO[1] = __builtin_amdgcn_mfma_f32_16x16x32_bf16(pa0, vf01, accO[1], 0, 0, 0); \
      bf16x8 pa1 = *reinterpret_cast<const bf16x8*>(sPw + ln * 64 + (((4 | g) ^ (ln & 7)) << 3)); \
      accO[0] = __builtin_amdgcn_mfma_f32_16x16x32_bf16(pa1, vf10, accO[0], 0, 0, 0); \
      accO[1] = __builtin_amdgcn_mfma_f32_16x16x32_bf16(pa1, vf11, accO[1], 0, 0, 0); \
    }                                                                          \
    __builtin_amdgcn_s_setprio(0);                                             \
  } while (0)

  for (int s2 = 0; s2 < 8; ++s2) {
    STEP(2 * s2,     ra0, ra1, ra2, ra3, rb0, rb1, rb2, rb3);
    STEP(2 * s2 + 1, rb0, rb1, rb2, rb3, ra0, ra1, ra2, ra3);
  }
#undef STEP

  // ---- epilogue: shuffle-reduce l, divide, bf16 write [b][n][c] ----
#pragma unroll
  for (int v = 0; v < 4; ++v) {
    float ls = l_lane[v];
    ls += __shfl_xor(ls, 1);
    ls += __shfl_xor(ls, 2);
    ls += __shfl_xor(ls, 4);
    ls += __shfl_xor(ls, 8);
    const float inv = 1.f / ls;
    const size_t row = (size_t)b * NPIX + i0 + (iw << 4) + (g << 2) + v;
    aout[row * DATTN + (h << 5) + ln]      = f2bf(accO[0][v] * inv);
    aout[row * DATTN + (h << 5) + 16 + ln] = f2bf(accO[1][v] * inv);
  }
}

// ---------------------------------------------------------------------------
// Proj GEMM (MFMA): out[b][o][n] = sum_k Wp[o,k] * A[b][n][k] + bias[o], f32 out.
// ---------------------------------------------------------------------------
__global__ __launch_bounds__(256) void gemm_proj_mfma(const u16* __restrict__ wp,
                                                      const u16* __restrict__ at,
                                                      const float* __restrict__ bias,
                                                      float* __restrict__ out) {
  __shared__ __align__(16) u16 sA[64 * 64];
  __shared__ __align__(16) u16 sB[128 * 64];
  const int t  = threadIdx.x;
  const int w  = t >> 6, l = t & 63, g = l >> 4, ln = l & 15;
  const int n0 = blockIdx.x * 128;
  const int o0 = blockIdx.y * 64;
  const int b  = blockIdx.z;
  const int wm = w >> 1, wn = w & 1;

  const u16* wbase = wp + (size_t)o0 * DATTN;
  const u16* abase = at + ((size_t)b * NPIX + n0) * DATTN;

  f32x4 acc[2][4];
#pragma unroll
  for (int mi = 0; mi < 2; ++mi)
#pragma unroll
    for (int ni = 0; ni < 4; ++ni) acc[mi][ni] = {0.f, 0.f, 0.f, 0.f};

  for (int k0 = 0; k0 < DATTN; k0 += 64) {
#pragma unroll
    for (int i = 0; i < 2; ++i) {
      int chunk = i * 256 + (w << 6) + l;
      gl_lds16(wbase + ((size_t)(chunk >> 3)) * DATTN + k0 + ((chunk & 7) << 3),
               (char*)sA + i * 4096 + (w << 10));
    }
#pragma unroll
    for (int i = 0; i < 4; ++i) {
      int chunk = i * 256 + (w << 6) + l;
      gl_lds16(abase + ((size_t)(chunk >> 3)) * DATTN + k0 + ((chunk & 7) << 3),
               (char*)sB + i * 4096 + (w << 10));
    }
    __syncthreads();
#pragma unroll
    for (int kk = 0; kk < 64; kk += 32) {
      bf16x8 af[2], bfr[4];
#pragma unroll
      for (int mi = 0; mi < 2; ++mi)
        af[mi] = *reinterpret_cast<const bf16x8*>(&sA[((wm << 5) + (mi << 4) + ln) * 64 + kk + (g << 3)]);
#pragma unroll
      for (int ni = 0; ni < 4; ++ni)
        bfr[ni] = *reinterpret_cast<const bf16x8*>(&sB[((wn << 6) + (ni << 4) + ln) * 64 + kk + (g << 3)]);
#pragma unroll
      for (int mi = 0; mi < 2; ++mi)
#pragma unroll
        for (int ni = 0; ni < 4; ++ni)
          acc[mi][ni] = __builtin_amdgcn_mfma_f32_16x16x32_bf16(af[mi], bfr[ni], acc[mi][ni], 0, 0, 0);
    }
    __syncthreads();
  }

#pragma unroll
  for (int mi = 0; mi < 2; ++mi) {
    const int o = o0 + (wm << 5) + (mi << 4) + (g << 2);
    const float b0 = bias[o], b1 = bias[o + 1], b2 = bias[o + 2], b3 = bias[o + 3];
#pragma unroll
    for (int ni = 0; ni < 4; ++ni) {
      const int n = n0 + (wn << 6) + (ni << 4) + ln;
      float* op = &out[((size_t)b * DATTN + o) * NPIX + n];
      op[0]        = acc[mi][ni][0] + b0;
      op[NPIX]     = acc[mi][ni][1] + b1;
      op[2 * NPIX] = acc[mi][ni][2] + b2;
      op[3 * NPIX] = acc[mi][ni][3] + b3;
    }
  }
}

extern "C" void kernel_launch(void* const* d_in, const int* in_sizes, int n_in,
                              void* d_out, int out_size, void* d_ws, size_t ws_size,
                              hipStream_t stream) {
  (void)in_sizes; (void)n_in; (void)out_size; (void)ws_size;
  const float* x      = (const float*)d_in[0];
  const float* w_qkv  = (const float*)d_in[1];
  const float* b_qkv  = (const float*)d_in[2];
  const float* w_proj = (const float*)d_in[3];
  const float* b_proj = (const float*)d_in[4];
  const float* rel    = (const float*)d_in[5];
  float* out = (float*)d_out;

  u16* xt    = (u16*)d_ws;                                   // 4 MB
  u16* wq_bf = xt + (size_t)BATCH * NPIX * CIN;              // 1.5 MB
  u16* wp_bf = wq_bf + (size_t)O_QKV * CIN;                  // 0.5 MB
  u16* qt    = wp_bf + (size_t)DATTN * DATTN;                // 4 MB
  u16* kt    = qt + (size_t)BATCH * HEADS * NPIX * DH;       // 4 MB
  u16* vt    = kt + (size_t)BATCH * HEADS * NPIX * DH;       // 4 MB
  u16* aout  = vt + (size_t)BATCH * HEADS * NPIX * DH;       // 4 MB

  prep_w<<<1024, 256, 0, stream>>>(w_qkv, w_proj, wq_bf, wp_bf);
  prep_x<<<dim3(NPIX / 64, CIN / 64, BATCH), 256, 0, stream>>>(x, xt);
  gemm_qkv_mfma<<<dim3(NPIX / 128, HEADS, BATCH), 256, 0, stream>>>(wq_bf, xt, b_qkv, qt, kt, vt);
  attn_mfma<<<1024, 256, 0, stream>>>(qt, kt, vt, rel, aout);
  gemm_proj_mfma<<<dim3(NPIX / 128, DATTN / 64, BATCH), 256, 0, stream>>>(wp_bf, aout, b_proj, out);
}

// Round 10
// 63.922 us; speedup vs baseline: 1.9073x; 1.9073x over previous
//
#include <hip/hip_runtime.h>
#include <cstdint>
#include <cstddef>

#define BATCH 4
#define CIN   512
#define NPIX  1024
#define HEADS 16
#define DH    32
#define DATTN 512
#define O_QKV 1536

typedef unsigned short u16;
typedef __bf16 bf16x4 __attribute__((ext_vector_type(4)));
typedef __bf16 bf16x8 __attribute__((ext_vector_type(8)));
typedef float  f32x4  __attribute__((ext_vector_type(4)));

typedef const __attribute__((address_space(1))) void g1_t;
typedef __attribute__((address_space(3))) void l3_t;

#if defined(__has_builtin)
#if __has_builtin(__builtin_amdgcn_exp2f)
#define EXP2(x) __builtin_amdgcn_exp2f(x)
#endif
#endif
#ifndef EXP2
#define EXP2(x) __expf((x) * 0.6931471805599453f)
#endif

__device__ __forceinline__ u16 f2bf(float f) {
  unsigned u = __float_as_uint(f);
  u += 0x7fffu + ((u >> 16) & 1u);
  return (u16)(u >> 16);
}

// async global->LDS, 16B per lane; lp must be wave-uniform (HW: base + lane*16)
__device__ __forceinline__ void gl_lds16(const void* gp, void* lp) {
  __builtin_amdgcn_global_load_lds((g1_t*)gp, (l3_t*)lp, 16, 0, 0);
}

// ---------------------------------------------------------------------------
// prep_w: convert w_qkv [1536][512] and w_proj [512][512] f32 -> bf16.
// ---------------------------------------------------------------------------
__global__ __launch_bounds__(256) void prep_w(const float* __restrict__ w1,
                                              const float* __restrict__ w2,
                                              u16* __restrict__ o1,
                                              u16* __restrict__ o2) {
  const int idx = blockIdx.x * 256 + threadIdx.x;   // float4 index
  const int n1 = (O_QKV * CIN) >> 2;                // 196608
  float4 v = (idx < n1) ? reinterpret_cast<const float4*>(w1)[idx]
                        : reinterpret_cast<const float4*>(w2)[idx - n1];
  uint2 pk = make_uint2((unsigned)f2bf(v.x) | ((unsigned)f2bf(v.y) << 16),
                        (unsigned)f2bf(v.z) | ((unsigned)f2bf(v.w) << 16));
  if (idx < n1) reinterpret_cast<uint2*>(o1)[idx] = pk;
  else          reinterpret_cast<uint2*>(o2)[idx - n1] = pk;
}

// ---------------------------------------------------------------------------
// prep_x: x [B][C][N] f32 -> xt [B][N][C] bf16 (tiled 64x64 LDS transpose)
// ---------------------------------------------------------------------------
__global__ __launch_bounds__(256) void prep_x(const float* __restrict__ x,
                                              u16* __restrict__ xt) {
  __shared__ float sT[64][65];
  const int t  = threadIdx.x;
  const int n0 = blockIdx.x * 64;
  const int c0 = blockIdx.y * 64;
  const int b  = blockIdx.z;
  const float* xb = x + ((size_t)b * CIN + c0) * NPIX + n0;
#pragma unroll
  for (int i = 0; i < 4; ++i) {
    int r   = i * 16 + (t >> 4);
    int col = (t & 15) << 2;
    float4 v = *reinterpret_cast<const float4*>(&xb[(size_t)r * NPIX + col]);
    sT[r][col + 0] = v.x; sT[r][col + 1] = v.y;
    sT[r][col + 2] = v.z; sT[r][col + 3] = v.w;
  }
  __syncthreads();
#pragma unroll
  for (int i = 0; i < 2; ++i) {
    int nl = t >> 2;
    int ch = (t & 3) + (i << 2);
    u16 tmp[8];
#pragma unroll
    for (int e = 0; e < 8; ++e) tmp[e] = f2bf(sT[(ch << 3) + e][nl]);
    *reinterpret_cast<uint4*>(&xt[((size_t)b * NPIX + n0 + nl) * CIN + c0 + (ch << 3)]) =
        *reinterpret_cast<uint4*>(tmp);
  }
}

// ---------------------------------------------------------------------------
// QKV GEMM (MFMA): M-tile=96 (one head), N-tile=128, BK=64, 4 waves.
// Epilogue: +bias, bf16; q PRE-SCALED by scale*log2e (attn uses exp2 domain).
// qt/kt [b][h][n][32], vt [b][h][d][n].
// ---------------------------------------------------------------------------
__global__ __launch_bounds__(256) void gemm_qkv_mfma(const u16* __restrict__ wq,
                                                     const u16* __restrict__ xt,
                                                     const float* __restrict__ bias,
                                                     u16* __restrict__ qt,
                                                     u16* __restrict__ kt,
                                                     u16* __restrict__ vt) {
  __shared__ __align__(16) u16 sA[96 * 64];
  __shared__ __align__(16) u16 sB[128 * 64];
  const int t  = threadIdx.x;
  const int w  = t >> 6, l = t & 63, g = l >> 4, ln = l & 15;
  const int n0 = blockIdx.x * 128;
  const int h  = blockIdx.y;
  const int b  = blockIdx.z;
  const int wm = w >> 1, wn = w & 1;

  const u16* wbase = wq + (size_t)h * 96 * CIN;
  const u16* xbase = xt + ((size_t)b * NPIX + n0) * CIN;

  f32x4 acc[3][4];
#pragma unroll
  for (int mi = 0; mi < 3; ++mi)
#pragma unroll
    for (int ni = 0; ni < 4; ++ni) acc[mi][ni] = {0.f, 0.f, 0.f, 0.f};

  for (int k0 = 0; k0 < CIN; k0 += 64) {
#pragma unroll
    for (int i = 0; i < 3; ++i) {
      int chunk = i * 256 + (w << 6) + l;
      gl_lds16(wbase + ((size_t)(chunk >> 3)) * CIN + k0 + ((chunk & 7) << 3),
               (char*)sA + i * 4096 + (w << 10));
    }
#pragma unroll
    for (int i = 0; i < 4; ++i) {
      int chunk = i * 256 + (w << 6) + l;
      gl_lds16(xbase + ((size_t)(chunk >> 3)) * CIN + k0 + ((chunk & 7) << 3),
               (char*)sB + i * 4096 + (w << 10));
    }
    __syncthreads();
#pragma unroll
    for (int kk = 0; kk < 64; kk += 32) {
      bf16x8 af[3], bfr[4];
#pragma unroll
      for (int mi = 0; mi < 3; ++mi)
        af[mi] = *reinterpret_cast<const bf16x8*>(&sA[(48 * wm + 16 * mi + ln) * 64 + kk + (g << 3)]);
#pragma unroll
      for (int ni = 0; ni < 4; ++ni)
        bfr[ni] = *reinterpret_cast<const bf16x8*>(&sB[((wn << 6) + (ni << 4) + ln) * 64 + kk + (g << 3)]);
#pragma unroll
      for (int mi = 0; mi < 3; ++mi)
#pragma unroll
        for (int ni = 0; ni < 4; ++ni)
          acc[mi][ni] = __builtin_amdgcn_mfma_f32_16x16x32_bf16(af[mi], bfr[ni], acc[mi][ni], 0, 0, 0);
    }
    __syncthreads();
  }

  const float QSC = 0.17677669529663687f * 1.4426950408889634f;  // scale*log2e
  const float* bh = bias + h * 96;
#pragma unroll
  for (int mi = 0; mi < 3; ++mi) {
    const int sec = 48 * wm + 16 * mi;
    const int rb  = sec + (g << 2);
    const float b0 = bh[rb + 0], b1 = bh[rb + 1], b2 = bh[rb + 2], b3 = bh[rb + 3];
#pragma unroll
    for (int ni = 0; ni < 4; ++ni) {
      const int n = n0 + (wn << 6) + (ni << 4) + ln;
      f32x4 a = acc[mi][ni];
      float v0 = a[0] + b0, v1 = a[1] + b1, v2 = a[2] + b2, v3 = a[3] + b3;
      if (sec < 32) { v0 *= QSC; v1 *= QSC; v2 *= QSC; v3 *= QSC; }
      u16 e0 = f2bf(v0), e1 = f2bf(v1), e2 = f2bf(v2), e3 = f2bf(v3);
      if (sec < 32) {
        const int d = sec + (g << 2);
        uint2 pk = make_uint2((unsigned)e0 | ((unsigned)e1 << 16),
                              (unsigned)e2 | ((unsigned)e3 << 16));
        *reinterpret_cast<uint2*>(&qt[(((size_t)(b * HEADS + h)) * NPIX + n) * DH + d]) = pk;
      } else if (sec < 64) {
        const int d = sec - 32 + (g << 2);
        uint2 pk = make_uint2((unsigned)e0 | ((unsigned)e1 << 16),
                              (unsigned)e2 | ((unsigned)e3 << 16));
        *reinterpret_cast<uint2*>(&kt[(((size_t)(b * HEADS + h)) * NPIX + n) * DH + d]) = pk;
      } else {
        const int d = sec - 64 + (g << 2);
        u16* vp = &vt[(((size_t)(b * HEADS + h)) * DH + d) * NPIX + n];
        vp[0] = e0; vp[NPIX] = e1; vp[2 * NPIX] = e2; vp[3 * NPIX] = e3;
      }
    }
  }
}

// ---------------------------------------------------------------------------
// MFMA flash attention v10 = round-8 compute core, per-batch 256-thr blocks.
// Block = (b, h, 64-row i-tile), 4 waves (iw = 16 rows each), 16 j-steps of 64,
// ONE __syncthreads per step; K/V double-buffered via global_load_lds with
// pre-swizzled global source (LDS dest linear).
// LDS 24KB -> 6 blocks/CU (24 waves, 75% cap); barriers couple only 4 waves,
// other resident blocks fill the drain stalls.
// Grid 1024: xcd=bid&7, sl=bid>>3; b=sl&3 (siblings dist-8: same XCD, adjacent
// -> rel L2 reuse; rel is L3-resident anyway), i0=((sl>>2)&15)<<6,
// h=(xcd<<1)|(sl>>6).
// K LDS: [32 packed rows r=j>>1][8 slots 16B], slot^=(r&7)^((r>>3)&1).
// V LDS: [32 d][8 slots 16B], slot^=(d&7).
// sP per wave: [16 rows][8 slots 16B], slot^=(row&7); b64 half-slot writes.
// ---------------------------------------------------------------------------
__global__ __launch_bounds__(256, 4) void attn_mfma(const u16* __restrict__ qt,
                                                    const u16* __restrict__ kt,
                                                    const u16* __restrict__ vt,
                                                    const float* __restrict__ rel,
                                                    u16* __restrict__ aout) {
  __shared__ __align__(16) u16 sK[2][2048];      // [buf][32r][8slot][8]   8KB
  __shared__ __align__(16) u16 sV[2][2048];      // [buf][32d][8slot][8]   8KB
  __shared__ __align__(16) u16 sP[4][1024];      // per-wave [16][8slot][8] 8KB

  const int t  = threadIdx.x;
  const int w  = t >> 6, l = t & 63, g = l >> 4, ln = l & 15;
  const int bid = blockIdx.x;
  const int xcd = bid & 7, sl = bid >> 3;   // sl 0..127
  const int b   = sl & 3;
  const int i0  = ((sl >> 2) & 15) << 6;
  const int h   = (xcd << 1) | (sl >> 6);
  const int iw  = w;                        // i-segment (16 rows)

  const size_t bh = (size_t)(b * HEADS + h);

  // staging (per-thread constant): thread t stages K chunk t and V chunk t.
  // c = t -> r = c>>3 (packed row / d row), slot = c&7 (XOR-swizzled source).
  const int sc_r  = t >> 3;
  const int sc_kc = (t & 7) ^ (sc_r & 7) ^ ((sc_r >> 3) & 1);  // K logical chunk
  const int sc_vc = (t & 7) ^ (sc_r & 7);                      // V logical chunk
  const u16* ksrc = kt + (bh * NPIX + ((sc_r << 1) | (sc_kc >> 2))) * DH +
                    ((sc_kc & 3) << 3);
  const u16* vsrc = vt + (bh * DH + sc_r) * NPIX + (sc_vc << 3);
  char* kdst = (char*)&sK[0][0] + (w << 10);
  char* vdst = (char*)&sV[0][0] + (w << 10);

#define STAGE(s_, p_) do {                                          \
    gl_lds16(ksrc + (size_t)(s_) * 2048, kdst + (p_) * 4096);       \
    gl_lds16(vsrc + (size_t)(s_) * 64,   vdst + (p_) * 4096);       \
  } while (0)

  STAGE(0, 0);

  // Q fragment (pre-scaled by scale*log2e): lane -> row i0+16*iw+ln, k=8g..+8
  bf16x8 qf = *reinterpret_cast<const bf16x8*>(
      qt + (bh * NPIX + i0 + (iw << 4) + ln) * DH + (g << 3));

  // rel: rows i0+16iw+4g+v, cols s*64 + 4ln + (0..3)
  const float* relp = rel + ((size_t)h * NPIX + i0 + (iw << 4) + (g << 2)) * NPIX +
                      (ln << 2);
  f32x4 relA4[4], relB4[4];
#pragma unroll
  for (int v = 0; v < 4; ++v)
    relA4[v] = *reinterpret_cast<const f32x4*>(relp + (size_t)v * NPIX);

  f32x4 vzero = {0.f, 0.f, 0.f, 0.f};
  f32x4 accO[2] = {vzero, vzero};
  f32x4 l_lane = vzero;

  u16* sPw = &sP[w][0];
  const float LOG2E = 1.4426950408889634f;

  for (int s = 0; s < 16; ++s) {
    const int p = s & 1;
    __syncthreads();                        // buf p staged; buf p^1 free
    if (s < 15) {
      STAGE(s + 1, p ^ 1);
#pragma unroll
      for (int v = 0; v < 4; ++v)
        relB4[v] = *reinterpret_cast<const f32x4*>(relp + (size_t)v * NPIX + ((s + 1) << 6));
    }

    const u16* Kb = &sK[p][0];
    const u16* Vb = &sV[p][0];

    // ---- S' = Q'^T K: fragment jj covers cols j = 4*ln + jj ----
    f32x4 sfr[4];
    __builtin_amdgcn_s_setprio(1);
#pragma unroll
    for (int jj = 0; jj < 4; ++jj) {
      const int r  = (ln << 1) + (jj >> 1);
      const int ks = ((((jj & 1) << 2) | g) ^ (r & 7)) ^ ((r >> 3) & 1);
      bf16x8 kf = *reinterpret_cast<const bf16x8*>(Kb + r * 64 + ks * 8);
      sfr[jj] = __builtin_amdgcn_mfma_f32_16x16x32_bf16(qf, kf, vzero, 0, 0, 0);
    }
    __builtin_amdgcn_s_setprio(0);

    // ---- P = exp2(S' + rel*log2e); swizzled b64 write per row ----
#pragma unroll
    for (int v = 0; v < 4; ++v) {
      float p0 = EXP2(fmaf(relA4[v][0], LOG2E, sfr[0][v]));
      float p1 = EXP2(fmaf(relA4[v][1], LOG2E, sfr[1][v]));
      float p2 = EXP2(fmaf(relA4[v][2], LOG2E, sfr[2][v]));
      float p3 = EXP2(fmaf(relA4[v][3], LOG2E, sfr[3][v]));
      l_lane[v] += (p0 + p1) + (p2 + p3);
      bf16x4 pk;
      pk[0] = (__bf16)p0; pk[1] = (__bf16)p1; pk[2] = (__bf16)p2; pk[3] = (__bf16)p3;
      const int rw = (g << 2) + v;
      *reinterpret_cast<bf16x4*>(
          sPw + rw * 64 + ((((ln >> 1) ^ (rw & 7)) << 3) | ((ln & 1) << 2))) = pk;
    }

    // ---- PV: acc[i][d] += P[i,j] * V[d,j] ----
    __builtin_amdgcn_s_setprio(1);
#pragma unroll
    for (int kc = 0; kc < 2; ++kc) {
      const int lc = (kc << 2) | g;
      bf16x8 pa = *reinterpret_cast<const bf16x8*>(sPw + ln * 64 + ((lc ^ (ln & 7)) << 3));
#pragma unroll
      for (int dc = 0; dc < 2; ++dc) {
        const int d  = (dc << 4) + ln;
        const int vs = lc ^ (d & 7);
        bf16x8 vf = *reinterpret_cast<const bf16x8*>(Vb + d * 64 + vs * 8);
        accO[dc] = __builtin_amdgcn_mfma_f32_16x16x32_bf16(pa, vf, accO[dc], 0, 0, 0);
      }
    }
    __builtin_amdgcn_s_setprio(0);

    if (s < 15) {
#pragma unroll
      for (int v = 0; v < 4; ++v) relA4[v] = relB4[v];
    }
  }
#undef STAGE

  // ---- epilogue: shuffle-reduce l, divide, bf16 write [b][n][c] ----
#pragma unroll
  for (int v = 0; v < 4; ++v) {
    float ls = l_lane[v];
    ls += __shfl_xor(ls, 1);
    ls += __shfl_xor(ls, 2);
    ls += __shfl_xor(ls, 4);
    ls += __shfl_xor(ls, 8);
    const float inv = 1.f / ls;
    const size_t row = (size_t)b * NPIX + i0 + (iw << 4) + (g << 2) + v;
    aout[row * DATTN + (h << 5) + ln]      = f2bf(accO[0][v] * inv);
    aout[row * DATTN + (h << 5) + 16 + ln] = f2bf(accO[1][v] * inv);
  }
}

// ---------------------------------------------------------------------------
// Proj GEMM (MFMA): out[b][o][n] = sum_k Wp[o,k] * A[b][n][k] + bias[o], f32 out.
// ---------------------------------------------------------------------------
__global__ __launch_bounds__(256) void gemm_proj_mfma(const u16* __restrict__ wp,
                                                      const u16* __restrict__ at,
                                                      const float* __restrict__ bias,
                                                      float* __restrict__ out) {
  __shared__ __align__(16) u16 sA[64 * 64];
  __shared__ __align__(16) u16 sB[128 * 64];
  const int t  = threadIdx.x;
  const int w  = t >> 6, l = t & 63, g = l >> 4, ln = l & 15;
  const int n0 = blockIdx.x * 128;
  const int o0 = blockIdx.y * 64;
  const int b  = blockIdx.z;
  const int wm = w >> 1, wn = w & 1;

  const u16* wbase = wp + (size_t)o0 * DATTN;
  const u16* abase = at + ((size_t)b * NPIX + n0) * DATTN;

  f32x4 acc[2][4];
#pragma unroll
  for (int mi = 0; mi < 2; ++mi)
#pragma unroll
    for (int ni = 0; ni < 4; ++ni) acc[mi][ni] = {0.f, 0.f, 0.f, 0.f};

  for (int k0 = 0; k0 < DATTN; k0 += 64) {
#pragma unroll
    for (int i = 0; i < 2; ++i) {
      int chunk = i * 256 + (w << 6) + l;
      gl_lds16(wbase + ((size_t)(chunk >> 3)) * DATTN + k0 + ((chunk & 7) << 3),
               (char*)sA + i * 4096 + (w << 10));
    }
#pragma unroll
    for (int i = 0; i < 4; ++i) {
      int chunk = i * 256 + (w << 6) + l;
      gl_lds16(abase + ((size_t)(chunk >> 3)) * DATTN + k0 + ((chunk & 7) << 3),
               (char*)sB + i * 4096 + (w << 10));
    }
    __syncthreads();
#pragma unroll
    for (int kk = 0; kk < 64; kk += 32) {
      bf16x8 af[2], bfr[4];
#pragma unroll
      for (int mi = 0; mi < 2; ++mi)
        af[mi] = *reinterpret_cast<const bf16x8*>(&sA[((wm << 5) + (mi << 4) + ln) * 64 + kk + (g << 3)]);
#pragma unroll
      for (int ni = 0; ni < 4; ++ni)
        bfr[ni] = *reinterpret_cast<const bf16x8*>(&sB[((wn << 6) + (ni << 4) + ln) * 64 + kk + (g << 3)]);
#pragma unroll
      for (int mi = 0; mi < 2; ++mi)
#pragma unroll
        for (int ni = 0; ni < 4; ++ni)
          acc[mi][ni] = __builtin_amdgcn_mfma_f32_16x16x32_bf16(af[mi], bfr[ni], acc[mi][ni], 0, 0, 0);
    }
    __syncthreads();
  }

#pragma unroll
  for (int mi = 0; mi < 2; ++mi) {
    const int o = o0 + (wm << 5) + (mi << 4) + (g << 2);
    const float b0 = bias[o], b1 = bias[o + 1], b2 = bias[o + 2], b3 = bias[o + 3];
#pragma unroll
    for (int ni = 0; ni < 4; ++ni) {
      const int n = n0 + (wn << 6) + (ni << 4) + ln;
      float* op = &out[((size_t)b * DATTN + o) * NPIX + n];
      op[0]        = acc[mi][ni][0] + b0;
      op[NPIX]     = acc[mi][ni][1] + b1;
      op[2 * NPIX] = acc[mi][ni][2] + b2;
      op[3 * NPIX] = acc[mi][ni][3] + b3;
    }
  }
}

extern "C" void kernel_launch(void* const* d_in, const int* in_sizes, int n_in,
                              void* d_out, int out_size, void* d_ws, size_t ws_size,
                              hipStream_t stream) {
  (void)in_sizes; (void)n_in; (void)out_size; (void)ws_size;
  const float* x      = (const float*)d_in[0];
  const float* w_qkv  = (const float*)d_in[1];
  const float* b_qkv  = (const float*)d_in[2];
  const float* w_proj = (const float*)d_in[3];
  const float* b_proj = (const float*)d_in[4];
  const float* rel    = (const float*)d_in[5];
  float* out = (float*)d_out;

  u16* xt    = (u16*)d_ws;                                   // 4 MB
  u16* wq_bf = xt + (size_t)BATCH * NPIX * CIN;              // 1.5 MB
  u16* wp_bf = wq_bf + (size_t)O_QKV * CIN;                  // 0.5 MB
  u16* qt    = wp_bf + (size_t)DATTN * DATTN;                // 4 MB
  u16* kt    = qt + (size_t)BATCH * HEADS * NPIX * DH;       // 4 MB
  u16* vt    = kt + (size_t)BATCH * HEADS * NPIX * DH;       // 4 MB
  u16* aout  = vt + (size_t)BATCH * HEADS * NPIX * DH;       // 4 MB

  prep_w<<<1024, 256, 0, stream>>>(w_qkv, w_proj, wq_bf, wp_bf);
  prep_x<<<dim3(NPIX / 64, CIN / 64, BATCH), 256, 0, stream>>>(x, xt);
  gemm_qkv_mfma<<<dim3(NPIX / 128, HEADS, BATCH), 256, 0, stream>>>(wq_bf, xt, b_qkv, qt, kt, vt);
  attn_mfma<<<1024, 256, 0, stream>>>(qt, kt, vt, rel, aout);
  gemm_proj_mfma<<<dim3(NPIX / 128, DATTN / 64, BATCH), 256, 0, stream>>>(wp_bf, aout, b_proj, out);
}

// Round 11
// 63.613 us; speedup vs baseline: 1.9166x; 1.0049x over previous
//
#include <hip/hip_runtime.h>
#include <cstdint>
#include <cstddef>

#define BATCH 4
#define CIN   512
#define NPIX  1024
#define HEADS 16
#define DH    32
#define DATTN 512
#define O_QKV 1536

typedef unsigned short u16;
typedef __bf16 bf16x4 __attribute__((ext_vector_type(4)));
typedef __bf16 bf16x8 __attribute__((ext_vector_type(8)));
typedef float  f32x4  __attribute__((ext_vector_type(4)));

typedef const __attribute__((address_space(1))) void g1_t;
typedef __attribute__((address_space(3))) void l3_t;

#if defined(__has_builtin)
#if __has_builtin(__builtin_amdgcn_exp2f)
#define EXP2(x) __builtin_amdgcn_exp2f(x)
#endif
#endif
#ifndef EXP2
#define EXP2(x) __expf((x) * 0.6931471805599453f)
#endif

__device__ __forceinline__ u16 f2bf(float f) {
  unsigned u = __float_as_uint(f);
  u += 0x7fffu + ((u >> 16) & 1u);
  return (u16)(u >> 16);
}

// async global->LDS, 16B per lane; lp must be wave-uniform (HW: base + lane*16)
__device__ __forceinline__ void gl_lds16(const void* gp, void* lp) {
  __builtin_amdgcn_global_load_lds((g1_t*)gp, (l3_t*)lp, 16, 0, 0);
}

// ---------------------------------------------------------------------------
// prep_w: convert w_qkv [1536][512] and w_proj [512][512] f32 -> bf16.
// ---------------------------------------------------------------------------
__global__ __launch_bounds__(256) void prep_w(const float* __restrict__ w1,
                                              const float* __restrict__ w2,
                                              u16* __restrict__ o1,
                                              u16* __restrict__ o2) {
  const int idx = blockIdx.x * 256 + threadIdx.x;   // float4 index
  const int n1 = (O_QKV * CIN) >> 2;                // 196608
  float4 v = (idx < n1) ? reinterpret_cast<const float4*>(w1)[idx]
                        : reinterpret_cast<const float4*>(w2)[idx - n1];
  uint2 pk = make_uint2((unsigned)f2bf(v.x) | ((unsigned)f2bf(v.y) << 16),
                        (unsigned)f2bf(v.z) | ((unsigned)f2bf(v.w) << 16));
  if (idx < n1) reinterpret_cast<uint2*>(o1)[idx] = pk;
  else          reinterpret_cast<uint2*>(o2)[idx - n1] = pk;
}

// ---------------------------------------------------------------------------
// prep_x: x [B][C][N] f32 -> xt [B][N][C] bf16 (tiled 64x64 LDS transpose)
// ---------------------------------------------------------------------------
__global__ __launch_bounds__(256) void prep_x(const float* __restrict__ x,
                                              u16* __restrict__ xt) {
  __shared__ float sT[64][65];
  const int t  = threadIdx.x;
  const int n0 = blockIdx.x * 64;
  const int c0 = blockIdx.y * 64;
  const int b  = blockIdx.z;
  const float* xb = x + ((size_t)b * CIN + c0) * NPIX + n0;
#pragma unroll
  for (int i = 0; i < 4; ++i) {
    int r   = i * 16 + (t >> 4);
    int col = (t & 15) << 2;
    float4 v = *reinterpret_cast<const float4*>(&xb[(size_t)r * NPIX + col]);
    sT[r][col + 0] = v.x; sT[r][col + 1] = v.y;
    sT[r][col + 2] = v.z; sT[r][col + 3] = v.w;
  }
  __syncthreads();
#pragma unroll
  for (int i = 0; i < 2; ++i) {
    int nl = t >> 2;
    int ch = (t & 3) + (i << 2);
    u16 tmp[8];
#pragma unroll
    for (int e = 0; e < 8; ++e) tmp[e] = f2bf(sT[(ch << 3) + e][nl]);
    *reinterpret_cast<uint4*>(&xt[((size_t)b * NPIX + n0 + nl) * CIN + c0 + (ch << 3)]) =
        *reinterpret_cast<uint4*>(tmp);
  }
}

// ---------------------------------------------------------------------------
// QKV GEMM (MFMA): M-tile=96 (one head), N-tile=128, BK=64, 4 waves.
// Epilogue: +bias, bf16; q PRE-SCALED by scale*log2e (attn uses exp2 domain).
// qt/kt [b][h][n][32], vt [b][h][d][n].
// ---------------------------------------------------------------------------
__global__ __launch_bounds__(256) void gemm_qkv_mfma(const u16* __restrict__ wq,
                                                     const u16* __restrict__ xt,
                                                     const float* __restrict__ bias,
                                                     u16* __restrict__ qt,
                                                     u16* __restrict__ kt,
                                                     u16* __restrict__ vt) {
  __shared__ __align__(16) u16 sA[96 * 64];
  __shared__ __align__(16) u16 sB[128 * 64];
  const int t  = threadIdx.x;
  const int w  = t >> 6, l = t & 63, g = l >> 4, ln = l & 15;
  const int n0 = blockIdx.x * 128;
  const int h  = blockIdx.y;
  const int b  = blockIdx.z;
  const int wm = w >> 1, wn = w & 1;

  const u16* wbase = wq + (size_t)h * 96 * CIN;
  const u16* xbase = xt + ((size_t)b * NPIX + n0) * CIN;

  f32x4 acc[3][4];
#pragma unroll
  for (int mi = 0; mi < 3; ++mi)
#pragma unroll
    for (int ni = 0; ni < 4; ++ni) acc[mi][ni] = {0.f, 0.f, 0.f, 0.f};

  for (int k0 = 0; k0 < CIN; k0 += 64) {
#pragma unroll
    for (int i = 0; i < 3; ++i) {
      int chunk = i * 256 + (w << 6) + l;
      gl_lds16(wbase + ((size_t)(chunk >> 3)) * CIN + k0 + ((chunk & 7) << 3),
               (char*)sA + i * 4096 + (w << 10));
    }
#pragma unroll
    for (int i = 0; i < 4; ++i) {
      int chunk = i * 256 + (w << 6) + l;
      gl_lds16(xbase + ((size_t)(chunk >> 3)) * CIN + k0 + ((chunk & 7) << 3),
               (char*)sB + i * 4096 + (w << 10));
    }
    __syncthreads();
#pragma unroll
    for (int kk = 0; kk < 64; kk += 32) {
      bf16x8 af[3], bfr[4];
#pragma unroll
      for (int mi = 0; mi < 3; ++mi)
        af[mi] = *reinterpret_cast<const bf16x8*>(&sA[(48 * wm + 16 * mi + ln) * 64 + kk + (g << 3)]);
#pragma unroll
      for (int ni = 0; ni < 4; ++ni)
        bfr[ni] = *reinterpret_cast<const bf16x8*>(&sB[((wn << 6) + (ni << 4) + ln) * 64 + kk + (g << 3)]);
#pragma unroll
      for (int mi = 0; mi < 3; ++mi)
#pragma unroll
        for (int ni = 0; ni < 4; ++ni)
          acc[mi][ni] = __builtin_amdgcn_mfma_f32_16x16x32_bf16(af[mi], bfr[ni], acc[mi][ni], 0, 0, 0);
    }
    __syncthreads();
  }

  const float QSC = 0.17677669529663687f * 1.4426950408889634f;  // scale*log2e
  const float* bh = bias + h * 96;
#pragma unroll
  for (int mi = 0; mi < 3; ++mi) {
    const int sec = 48 * wm + 16 * mi;
    const int rb  = sec + (g << 2);
    const float b0 = bh[rb + 0], b1 = bh[rb + 1], b2 = bh[rb + 2], b3 = bh[rb + 3];
#pragma unroll
    for (int ni = 0; ni < 4; ++ni) {
      const int n = n0 + (wn << 6) + (ni << 4) + ln;
      f32x4 a = acc[mi][ni];
      float v0 = a[0] + b0, v1 = a[1] + b1, v2 = a[2] + b2, v3 = a[3] + b3;
      if (sec < 32) { v0 *= QSC; v1 *= QSC; v2 *= QSC; v3 *= QSC; }
      u16 e0 = f2bf(v0), e1 = f2bf(v1), e2 = f2bf(v2), e3 = f2bf(v3);
      if (sec < 32) {
        const int d = sec + (g << 2);
        uint2 pk = make_uint2((unsigned)e0 | ((unsigned)e1 << 16),
                              (unsigned)e2 | ((unsigned)e3 << 16));
        *reinterpret_cast<uint2*>(&qt[(((size_t)(b * HEADS + h)) * NPIX + n) * DH + d]) = pk;
      } else if (sec < 64) {
        const int d = sec - 32 + (g << 2);
        uint2 pk = make_uint2((unsigned)e0 | ((unsigned)e1 << 16),
                              (unsigned)e2 | ((unsigned)e3 << 16));
        *reinterpret_cast<uint2*>(&kt[(((size_t)(b * HEADS + h)) * NPIX + n) * DH + d]) = pk;
      } else {
        const int d = sec - 64 + (g << 2);
        u16* vp = &vt[(((size_t)(b * HEADS + h)) * DH + d) * NPIX + n];
        vp[0] = e0; vp[NPIX] = e1; vp[2 * NPIX] = e2; vp[3 * NPIX] = e3;
      }
    }
  }
}

// ---------------------------------------------------------------------------
// MFMA flash attention v11 = round-10 compute core + in-block j-split.
// Block = (b, h, 64-row i-tile): 512 thr, 8 waves = 4 iw (16 i-rows) x 2 jh
// (j-halves of 512). Each wave: 8 j-steps of 64, ONE __syncthreads per step.
// 24 waves/CU target: LDS 48KB -> 3 blocks/CU x 8 waves (the r4/5/8/10
// plateau was 16 waves/CU; occupancy is the proven dial).
// __launch_bounds__(512,4): VGPR cap 128 -- r5 measured 52 VGPR no spill at
// this setting; (512,6) spilled (r6/r7).
// Grid 1024: xcd=bid&7, sl=bid>>3; b=sl&3 (siblings bid-dist 8: same XCD,
// adjacent -> rel L2 reuse, r8/r10 verified FETCH 39MB), i0=((sl>>2)&15)<<6,
// h=(xcd<<1)|(sl>>6).
// K LDS per (buf,jh): [32 packed rows r=j>>1][8 slots 16B], slot^=(r&7)^((r>>3)&1).
// V LDS per (buf,jh): [32 d][8 slots 16B], slot^=(d&7).
// sP per wave: [16 rows][8 slots 16B], slot^=(row&7); b64 half-slot writes.
// j-half partials (O,l) merged via LDS scratch (r7-verified code path).
// ---------------------------------------------------------------------------
__global__ __launch_bounds__(512, 4) void attn_mfma(const u16* __restrict__ qt,
                                                    const u16* __restrict__ kt,
                                                    const u16* __restrict__ vt,
                                                    const float* __restrict__ rel,
                                                    u16* __restrict__ aout) {
  __shared__ __align__(16) u16 sK[2][2][2048];   // [buf][jh][32r][8slot][8] 16KB
  __shared__ __align__(16) u16 sV[2][2][2048];   // [buf][jh][32d][8slot][8] 16KB
  __shared__ __align__(16) u16 sP[8][1024];      // per-wave [16][8slot][8]  16KB

  const int t  = threadIdx.x;
  const int w  = t >> 6, l = t & 63, g = l >> 4, ln = l & 15;
  const int bid = blockIdx.x;
  const int xcd = bid & 7, sl = bid >> 3;   // sl 0..127
  const int b   = sl & 3;
  const int i0  = ((sl >> 2) & 15) << 6;
  const int h   = (xcd << 1) | (sl >> 6);
  const int iw  = w & 3;                    // i-segment (16 rows)
  const int jh  = w >> 2;                   // j-half (512 cols)

  const size_t bh = (size_t)(b * HEADS + h);

  // staging (per-thread constant): wave w stages quarter iw of j-half (w>>2).
  // Local row lr = l>>3 (0..7) within quarter; ls = l&7 = swizzled slot.
  const int lr = l >> 3, ls = l & 7;
  const int sjh = w >> 2;
  const int kcl = ls ^ lr ^ (iw & 1);                 // K logical chunk
  const int kj  = (iw << 4) + (lr << 1) + (kcl >> 2); // j within half
  const u16* ksrc = kt + (bh * NPIX + (sjh << 9) + kj) * DH + ((kcl & 3) << 3);
  const int vcl = ls ^ lr;                            // V logical chunk
  const int vd  = (iw << 3) + lr;                     // d row
  const u16* vsrc = vt + (bh * DH + vd) * NPIX + (sjh << 9) + (vcl << 3);
  char* kdst = (char*)&sK[0][sjh][0] + (iw << 10);
  char* vdst = (char*)&sV[0][sjh][0] + (iw << 10);

#define STAGE(s_, p_) do {                                          \
    gl_lds16(ksrc + (size_t)(s_) * 2048, kdst + (p_) * 8192);       \
    gl_lds16(vsrc + (size_t)(s_) * 64,   vdst + (p_) * 8192);       \
  } while (0)

  STAGE(0, 0);

  // Q fragment (pre-scaled by scale*log2e): lane -> row i0+16*iw+ln, k=8g..+8
  bf16x8 qf = *reinterpret_cast<const bf16x8*>(
      qt + (bh * NPIX + i0 + (iw << 4) + ln) * DH + (g << 3));

  // rel: rows i0+16iw+4g+v, cols jh*512 + s*64 + 4ln + (0..3)
  const float* relp = rel + ((size_t)h * NPIX + i0 + (iw << 4) + (g << 2)) * NPIX +
                      (jh << 9) + (ln << 2);
  f32x4 relA4[4], relB4[4];
#pragma unroll
  for (int v = 0; v < 4; ++v)
    relA4[v] = *reinterpret_cast<const f32x4*>(relp + (size_t)v * NPIX);

  f32x4 vzero = {0.f, 0.f, 0.f, 0.f};
  f32x4 accO[2] = {vzero, vzero};
  f32x4 l_lane = vzero;

  u16* sPw = &sP[w][0];
  const float LOG2E = 1.4426950408889634f;

  for (int s = 0; s < 8; ++s) {
    const int p = s & 1;
    __syncthreads();                        // buf p staged; buf p^1 free
    if (s < 7) {
      STAGE(s + 1, p ^ 1);
#pragma unroll
      for (int v = 0; v < 4; ++v)
        relB4[v] = *reinterpret_cast<const f32x4*>(relp + (size_t)v * NPIX + ((s + 1) << 6));
    }

    const u16* Kb = &sK[p][jh][0];
    const u16* Vb = &sV[p][jh][0];

    // ---- S' = Q'^T K: fragment jj covers cols j = 4*ln + jj ----
    f32x4 sfr[4];
    __builtin_amdgcn_s_setprio(1);
#pragma unroll
    for (int jj = 0; jj < 4; ++jj) {
      const int r  = (ln << 1) + (jj >> 1);
      const int ks = ((((jj & 1) << 2) | g) ^ (r & 7)) ^ ((r >> 3) & 1);
      bf16x8 kf = *reinterpret_cast<const bf16x8*>(Kb + r * 64 + ks * 8);
      sfr[jj] = __builtin_amdgcn_mfma_f32_16x16x32_bf16(qf, kf, vzero, 0, 0, 0);
    }
    __builtin_amdgcn_s_setprio(0);

    // ---- P = exp2(S' + rel*log2e); swizzled b64 write per row ----
#pragma unroll
    for (int v = 0; v < 4; ++v) {
      float p0 = EXP2(fmaf(relA4[v][0], LOG2E, sfr[0][v]));
      float p1 = EXP2(fmaf(relA4[v][1], LOG2E, sfr[1][v]));
      float p2 = EXP2(fmaf(relA4[v][2], LOG2E, sfr[2][v]));
      float p3 = EXP2(fmaf(relA4[v][3], LOG2E, sfr[3][v]));
      l_lane[v] += (p0 + p1) + (p2 + p3);
      bf16x4 pk;
      pk[0] = (__bf16)p0; pk[1] = (__bf16)p1; pk[2] = (__bf16)p2; pk[3] = (__bf16)p3;
      const int rw = (g << 2) + v;
      *reinterpret_cast<bf16x4*>(
          sPw + rw * 64 + ((((ln >> 1) ^ (rw & 7)) << 3) | ((ln & 1) << 2))) = pk;
    }

    // ---- PV: acc[i][d] += P[i,j] * V[d,j] ----
    __builtin_amdgcn_s_setprio(1);
#pragma unroll
    for (int kc = 0; kc < 2; ++kc) {
      const int lc = (kc << 2) | g;
      bf16x8 pa = *reinterpret_cast<const bf16x8*>(sPw + ln * 64 + ((lc ^ (ln & 7)) << 3));
#pragma unroll
      for (int dc = 0; dc < 2; ++dc) {
        const int d  = (dc << 4) + ln;
        const int vs = lc ^ (d & 7);
        bf16x8 vf = *reinterpret_cast<const bf16x8*>(Vb + d * 64 + vs * 8);
        accO[dc] = __builtin_amdgcn_mfma_f32_16x16x32_bf16(pa, vf, accO[dc], 0, 0, 0);
      }
    }
    __builtin_amdgcn_s_setprio(0);

    if (s < 7) {
#pragma unroll
      for (int v = 0; v < 4; ++v) relA4[v] = relB4[v];
    }
  }
#undef STAGE

  // ---- merge the two j-halves, then finalize (jh==0 waves write out) ----
  __syncthreads();
  float* mrg = (float*)&sK[0][0][0];        // 12.3 KB scratch over sK space
  if (jh == 1) {
    float* mp = mrg + ((size_t)((iw << 6) + l)) * 12;
    *reinterpret_cast<f32x4*>(mp + 0) = accO[0];
    *reinterpret_cast<f32x4*>(mp + 4) = accO[1];
    *reinterpret_cast<f32x4*>(mp + 8) = l_lane;
  }
  __syncthreads();
  if (jh == 0) {
    const float* mp = mrg + ((size_t)((iw << 6) + l)) * 12;
    f32x4 o0 = accO[0] + *reinterpret_cast<const f32x4*>(mp + 0);
    f32x4 o1 = accO[1] + *reinterpret_cast<const f32x4*>(mp + 4);
    f32x4 lv = l_lane + *reinterpret_cast<const f32x4*>(mp + 8);
#pragma unroll
    for (int v = 0; v < 4; ++v) {
      float ls2 = lv[v];
      ls2 += __shfl_xor(ls2, 1);
      ls2 += __shfl_xor(ls2, 2);
      ls2 += __shfl_xor(ls2, 4);
      ls2 += __shfl_xor(ls2, 8);
      const float inv = 1.f / ls2;
      const size_t row = (size_t)b * NPIX + i0 + (iw << 4) + (g << 2) + v;
      aout[row * DATTN + (h << 5) + ln]      = f2bf(o0[v] * inv);
      aout[row * DATTN + (h << 5) + 16 + ln] = f2bf(o1[v] * inv);
    }
  }
}

// ---------------------------------------------------------------------------
// Proj GEMM (MFMA): out[b][o][n] = sum_k Wp[o,k] * A[b][n][k] + bias[o], f32 out.
// ---------------------------------------------------------------------------
__global__ __launch_bounds__(256) void gemm_proj_mfma(const u16* __restrict__ wp,
                                                      const u16* __restrict__ at,
                                                      const float* __restrict__ bias,
                                                      float* __restrict__ out) {
  __shared__ __align__(16) u16 sA[64 * 64];
  __shared__ __align__(16) u16 sB[128 * 64];
  const int t  = threadIdx.x;
  const int w  = t >> 6, l = t & 63, g = l >> 4, ln = l & 15;
  const int n0 = blockIdx.x * 128;
  const int o0 = blockIdx.y * 64;
  const int b  = blockIdx.z;
  const int wm = w >> 1, wn = w & 1;

  const u16* wbase = wp + (size_t)o0 * DATTN;
  const u16* abase = at + ((size_t)b * NPIX + n0) * DATTN;

  f32x4 acc[2][4];
#pragma unroll
  for (int mi = 0; mi < 2; ++mi)
#pragma unroll
    for (int ni = 0; ni < 4; ++ni) acc[mi][ni] = {0.f, 0.f, 0.f, 0.f};

  for (int k0 = 0; k0 < DATTN; k0 += 64) {
#pragma unroll
    for (int i = 0; i < 2; ++i) {
      int chunk = i * 256 + (w << 6) + l;
      gl_lds16(wbase + ((size_t)(chunk >> 3)) * DATTN + k0 + ((chunk & 7) << 3),
               (char*)sA + i * 4096 + (w << 10));
    }
#pragma unroll
    for (int i = 0; i < 4; ++i) {
      int chunk = i * 256 + (w << 6) + l;
      gl_lds16(abase + ((size_t)(chunk >> 3)) * DATTN + k0 + ((chunk & 7) << 3),
               (char*)sB + i * 4096 + (w << 10));
    }
    __syncthreads();
#pragma unroll
    for (int kk = 0; kk < 64; kk += 32) {
      bf16x8 af[2], bfr[4];
#pragma unroll
      for (int mi = 0; mi < 2; ++mi)
        af[mi] = *reinterpret_cast<const bf16x8*>(&sA[((wm << 5) + (mi << 4) + ln) * 64 + kk + (g << 3)]);
#pragma unroll
      for (int ni = 0; ni < 4; ++ni)
        bfr[ni] = *reinterpret_cast<const bf16x8*>(&sB[((wn << 6) + (ni << 4) + ln) * 64 + kk + (g << 3)]);
#pragma unroll
      for (int mi = 0; mi < 2; ++mi)
#pragma unroll
        for (int ni = 0; ni < 4; ++ni)
          acc[mi][ni] = __builtin_amdgcn_mfma_f32_16x16x32_bf16(af[mi], bfr[ni], acc[mi][ni], 0, 0, 0);
    }
    __syncthreads();
  }

#pragma unroll
  for (int mi = 0; mi < 2; ++mi) {
    const int o = o0 + (wm << 5) + (mi << 4) + (g << 2);
    const float b0 = bias[o], b1 = bias[o + 1], b2 = bias[o + 2], b3 = bias[o + 3];
#pragma unroll
    for (int ni = 0; ni < 4; ++ni) {
      const int n = n0 + (wn << 6) + (ni << 4) + ln;
      float* op = &out[((size_t)b * DATTN + o) * NPIX + n];
      op[0]        = acc[mi][ni][0] + b0;
      op[NPIX]     = acc[mi][ni][1] + b1;
      op[2 * NPIX] = acc[mi][ni][2] + b2;
      op[3 * NPIX] = acc[mi][ni][3] + b3;
    }
  }
}

extern "C" void kernel_launch(void* const* d_in, const int* in_sizes, int n_in,
                              void* d_out, int out_size, void* d_ws, size_t ws_size,
                              hipStream_t stream) {
  (void)in_sizes; (void)n_in; (void)out_size; (void)ws_size;
  const float* x      = (const float*)d_in[0];
  const float* w_qkv  = (const float*)d_in[1];
  const float* b_qkv  = (const float*)d_in[2];
  const float* w_proj = (const float*)d_in[3];
  const float* b_proj = (const float*)d_in[4];
  const float* rel    = (const float*)d_in[5];
  float* out = (float*)d_out;

  u16* xt    = (u16*)d_ws;                                   // 4 MB
  u16* wq_bf = xt + (size_t)BATCH * NPIX * CIN;              // 1.5 MB
  u16* wp_bf = wq_bf + (size_t)O_QKV * CIN;                  // 0.5 MB
  u16* qt    = wp_bf + (size_t)DATTN * DATTN;                // 4 MB
  u16* kt    = qt + (size_t)BATCH * HEADS * NPIX * DH;       // 4 MB
  u16* vt    = kt + (size_t)BATCH * HEADS * NPIX * DH;       // 4 MB
  u16* aout  = vt + (size_t)BATCH * HEADS * NPIX * DH;       // 4 MB

  prep_w<<<1024, 256, 0, stream>>>(w_qkv, w_proj, wq_bf, wp_bf);
  prep_x<<<dim3(NPIX / 64, CIN / 64, BATCH), 256, 0, stream>>>(x, xt);
  gemm_qkv_mfma<<<dim3(NPIX / 128, HEADS, BATCH), 256, 0, stream>>>(wq_bf, xt, b_qkv, qt, kt, vt);
  attn_mfma<<<1024, 512, 0, stream>>>(qt, kt, vt, rel, aout);
  gemm_proj_mfma<<<dim3(NPIX / 128, DATTN / 64, BATCH), 256, 0, stream>>>(wp_bf, aout, b_proj, out);
}

// Round 12
// 63.132 us; speedup vs baseline: 1.9312x; 1.0076x over previous
//
#include <hip/hip_runtime.h>
#include <cstdint>
#include <cstddef>

#define BATCH 4
#define CIN   512
#define NPIX  1024
#define HEADS 16
#define DH    32
#define DATTN 512
#define O_QKV 1536

typedef unsigned short u16;
typedef __bf16 bf16x4 __attribute__((ext_vector_type(4)));
typedef __bf16 bf16x8 __attribute__((ext_vector_type(8)));
typedef float  f32x4  __attribute__((ext_vector_type(4)));

typedef const __attribute__((address_space(1))) void g1_t;
typedef __attribute__((address_space(3))) void l3_t;

#if defined(__has_builtin)
#if __has_builtin(__builtin_amdgcn_exp2f)
#define EXP2(x) __builtin_amdgcn_exp2f(x)
#endif
#endif
#ifndef EXP2
#define EXP2(x) __expf((x) * 0.6931471805599453f)
#endif

__device__ __forceinline__ u16 f2bf(float f) {
  unsigned u = __float_as_uint(f);
  u += 0x7fffu + ((u >> 16) & 1u);
  return (u16)(u >> 16);
}

// async global->LDS, 16B per lane; lp must be wave-uniform (HW: base + lane*16)
__device__ __forceinline__ void gl_lds16(const void* gp, void* lp) {
  __builtin_amdgcn_global_load_lds((g1_t*)gp, (l3_t*)lp, 16, 0, 0);
}

// ---------------------------------------------------------------------------
// prep_w: convert w_qkv [1536][512] and w_proj [512][512] f32 -> bf16.
// ---------------------------------------------------------------------------
__global__ __launch_bounds__(256) void prep_w(const float* __restrict__ w1,
                                              const float* __restrict__ w2,
                                              u16* __restrict__ o1,
                                              u16* __restrict__ o2) {
  const int idx = blockIdx.x * 256 + threadIdx.x;   // float4 index
  const int n1 = (O_QKV * CIN) >> 2;                // 196608
  float4 v = (idx < n1) ? reinterpret_cast<const float4*>(w1)[idx]
                        : reinterpret_cast<const float4*>(w2)[idx - n1];
  uint2 pk = make_uint2((unsigned)f2bf(v.x) | ((unsigned)f2bf(v.y) << 16),
                        (unsigned)f2bf(v.z) | ((unsigned)f2bf(v.w) << 16));
  if (idx < n1) reinterpret_cast<uint2*>(o1)[idx] = pk;
  else          reinterpret_cast<uint2*>(o2)[idx - n1] = pk;
}

// ---------------------------------------------------------------------------
// prep_x: x [B][C][N] f32 -> xt [B][N][C] bf16 (tiled 64x64 LDS transpose)
// ---------------------------------------------------------------------------
__global__ __launch_bounds__(256) void prep_x(const float* __restrict__ x,
                                              u16* __restrict__ xt) {
  __shared__ float sT[64][65];
  const int t  = threadIdx.x;
  const int n0 = blockIdx.x * 64;
  const int c0 = blockIdx.y * 64;
  const int b  = blockIdx.z;
  const float* xb = x + ((size_t)b * CIN + c0) * NPIX + n0;
#pragma unroll
  for (int i = 0; i < 4; ++i) {
    int r   = i * 16 + (t >> 4);
    int col = (t & 15) << 2;
    float4 v = *reinterpret_cast<const float4*>(&xb[(size_t)r * NPIX + col]);
    sT[r][col + 0] = v.x; sT[r][col + 1] = v.y;
    sT[r][col + 2] = v.z; sT[r][col + 3] = v.w;
  }
  __syncthreads();
#pragma unroll
  for (int i = 0; i < 2; ++i) {
    int nl = t >> 2;
    int ch = (t & 3) + (i << 2);
    u16 tmp[8];
#pragma unroll
    for (int e = 0; e < 8; ++e) tmp[e] = f2bf(sT[(ch << 3) + e][nl]);
    *reinterpret_cast<uint4*>(&xt[((size_t)b * NPIX + n0 + nl) * CIN + c0 + (ch << 3)]) =
        *reinterpret_cast<uint4*>(tmp);
  }
}

// ---------------------------------------------------------------------------
// QKV GEMM (MFMA): M-tile=96 (one head), N-tile=128, BK=64, 4 waves.
// Epilogue: +bias, bf16; q PRE-SCALED by scale*log2e (attn uses exp2 domain).
// qt/kt [b][h][n][32], vt [b][h][d][n].
// ---------------------------------------------------------------------------
__global__ __launch_bounds__(256) void gemm_qkv_mfma(const u16* __restrict__ wq,
                                                     const u16* __restrict__ xt,
                                                     const float* __restrict__ bias,
                                                     u16* __restrict__ qt,
                                                     u16* __restrict__ kt,
                                                     u16* __restrict__ vt) {
  __shared__ __align__(16) u16 sA[96 * 64];
  __shared__ __align__(16) u16 sB[128 * 64];
  const int t  = threadIdx.x;
  const int w  = t >> 6, l = t & 63, g = l >> 4, ln = l & 15;
  const int n0 = blockIdx.x * 128;
  const int h  = blockIdx.y;
  const int b  = blockIdx.z;
  const int wm = w >> 1, wn = w & 1;

  const u16* wbase = wq + (size_t)h * 96 * CIN;
  const u16* xbase = xt + ((size_t)b * NPIX + n0) * CIN;

  f32x4 acc[3][4];
#pragma unroll
  for (int mi = 0; mi < 3; ++mi)
#pragma unroll
    for (int ni = 0; ni < 4; ++ni) acc[mi][ni] = {0.f, 0.f, 0.f, 0.f};

  for (int k0 = 0; k0 < CIN; k0 += 64) {
#pragma unroll
    for (int i = 0; i < 3; ++i) {
      int chunk = i * 256 + (w << 6) + l;
      gl_lds16(wbase + ((size_t)(chunk >> 3)) * CIN + k0 + ((chunk & 7) << 3),
               (char*)sA + i * 4096 + (w << 10));
    }
#pragma unroll
    for (int i = 0; i < 4; ++i) {
      int chunk = i * 256 + (w << 6) + l;
      gl_lds16(xbase + ((size_t)(chunk >> 3)) * CIN + k0 + ((chunk & 7) << 3),
               (char*)sB + i * 4096 + (w << 10));
    }
    __syncthreads();
#pragma unroll
    for (int kk = 0; kk < 64; kk += 32) {
      bf16x8 af[3], bfr[4];
#pragma unroll
      for (int mi = 0; mi < 3; ++mi)
        af[mi] = *reinterpret_cast<const bf16x8*>(&sA[(48 * wm + 16 * mi + ln) * 64 + kk + (g << 3)]);
#pragma unroll
      for (int ni = 0; ni < 4; ++ni)
        bfr[ni] = *reinterpret_cast<const bf16x8*>(&sB[((wn << 6) + (ni << 4) + ln) * 64 + kk + (g << 3)]);
#pragma unroll
      for (int mi = 0; mi < 3; ++mi)
#pragma unroll
        for (int ni = 0; ni < 4; ++ni)
          acc[mi][ni] = __builtin_amdgcn_mfma_f32_16x16x32_bf16(af[mi], bfr[ni], acc[mi][ni], 0, 0, 0);
    }
    __syncthreads();
  }

  const float QSC = 0.17677669529663687f * 1.4426950408889634f;  // scale*log2e
  const float* bh = bias + h * 96;
#pragma unroll
  for (int mi = 0; mi < 3; ++mi) {
    const int sec = 48 * wm + 16 * mi;
    const int rb  = sec + (g << 2);
    const float b0 = bh[rb + 0], b1 = bh[rb + 1], b2 = bh[rb + 2], b3 = bh[rb + 3];
#pragma unroll
    for (int ni = 0; ni < 4; ++ni) {
      const int n = n0 + (wn << 6) + (ni << 4) + ln;
      f32x4 a = acc[mi][ni];
      float v0 = a[0] + b0, v1 = a[1] + b1, v2 = a[2] + b2, v3 = a[3] + b3;
      if (sec < 32) { v0 *= QSC; v1 *= QSC; v2 *= QSC; v3 *= QSC; }
      u16 e0 = f2bf(v0), e1 = f2bf(v1), e2 = f2bf(v2), e3 = f2bf(v3);
      if (sec < 32) {
        const int d = sec + (g << 2);
        uint2 pk = make_uint2((unsigned)e0 | ((unsigned)e1 << 16),
                              (unsigned)e2 | ((unsigned)e3 << 16));
        *reinterpret_cast<uint2*>(&qt[(((size_t)(b * HEADS + h)) * NPIX + n) * DH + d]) = pk;
      } else if (sec < 64) {
        const int d = sec - 32 + (g << 2);
        uint2 pk = make_uint2((unsigned)e0 | ((unsigned)e1 << 16),
                              (unsigned)e2 | ((unsigned)e3 << 16));
        *reinterpret_cast<uint2*>(&kt[(((size_t)(b * HEADS + h)) * NPIX + n) * DH + d]) = pk;
      } else {
        const int d = sec - 64 + (g << 2);
        u16* vp = &vt[(((size_t)(b * HEADS + h)) * DH + d) * NPIX + n];
        vp[0] = e0; vp[NPIX] = e1; vp[2 * NPIX] = e2; vp[3 * NPIX] = e3;
      }
    }
  }
}

// ---------------------------------------------------------------------------
// MFMA flash attention v12 = r11 structure + DEFERRED PV (one-step pipeline).
// At step s: PV(s-1) issues right after the barrier, using P(s-1) still in the
// wave-private sP (in-order same-wave DS: this step's P writes come later in
// program order) and V(s-1) fragments carried in 4 NAMED registers loaded at
// the end of step s-1 (before the barrier -> V LDS buffer re-stage is safe).
// Critical path per step loses the P-write->P-read lgkm round trip + PV block.
// Accumulation order per accO unchanged -> numerically identical to r11.
// Block: 512 thr, 8 waves = 4 iw x 2 jh; 8 j-steps; one barrier/step.
// LDS 48KB -> 3 blocks/CU; __launch_bounds__(512,4) (VGPR cap 128, no spill).
// Grid 1024: xcd=bid&7, sl=bid>>3; b=sl&3 (siblings bid-dist 8 -> same XCD,
// adjacent -> rel L2 reuse), i0=((sl>>2)&15)<<6, h=(xcd<<1)|(sl>>6).
// ---------------------------------------------------------------------------
__global__ __launch_bounds__(512, 4) void attn_mfma(const u16* __restrict__ qt,
                                                    const u16* __restrict__ kt,
                                                    const u16* __restrict__ vt,
                                                    const float* __restrict__ rel,
                                                    u16* __restrict__ aout) {
  __shared__ __align__(16) u16 sK[2][2][2048];   // [buf][jh][32r][8slot][8] 16KB
  __shared__ __align__(16) u16 sV[2][2][2048];   // [buf][jh][32d][8slot][8] 16KB
  __shared__ __align__(16) u16 sP[8][1024];      // per-wave [16][8slot][8]  16KB

  const int t  = threadIdx.x;
  const int w  = t >> 6, l = t & 63, g = l >> 4, ln = l & 15;
  const int bid = blockIdx.x;
  const int xcd = bid & 7, sl = bid >> 3;   // sl 0..127
  const int b   = sl & 3;
  const int i0  = ((sl >> 2) & 15) << 6;
  const int h   = (xcd << 1) | (sl >> 6);
  const int iw  = w & 3;                    // i-segment (16 rows)
  const int jh  = w >> 2;                   // j-half (512 cols)

  const size_t bh = (size_t)(b * HEADS + h);

  // staging (per-thread constant): wave w stages quarter iw of j-half (w>>2).
  const int lr = l >> 3, ls = l & 7;
  const int sjh = w >> 2;
  const int kcl = ls ^ lr ^ (iw & 1);                 // K logical chunk
  const int kj  = (iw << 4) + (lr << 1) + (kcl >> 2); // j within half
  const u16* ksrc = kt + (bh * NPIX + (sjh << 9) + kj) * DH + ((kcl & 3) << 3);
  const int vcl = ls ^ lr;                            // V logical chunk
  const int vd  = (iw << 3) + lr;                     // d row
  const u16* vsrc = vt + (bh * DH + vd) * NPIX + (sjh << 9) + (vcl << 3);
  char* kdst = (char*)&sK[0][sjh][0] + (iw << 10);
  char* vdst = (char*)&sV[0][sjh][0] + (iw << 10);

#define STAGE(s_, p_) do {                                          \
    gl_lds16(ksrc + (size_t)(s_) * 2048, kdst + (p_) * 8192);       \
    gl_lds16(vsrc + (size_t)(s_) * 64,   vdst + (p_) * 8192);       \
  } while (0)

  STAGE(0, 0);

  // Q fragment (pre-scaled by scale*log2e): lane -> row i0+16*iw+ln, k=8g..+8
  bf16x8 qf = *reinterpret_cast<const bf16x8*>(
      qt + (bh * NPIX + i0 + (iw << 4) + ln) * DH + (g << 3));

  // rel: rows i0+16iw+4g+v, cols jh*512 + s*64 + 4ln + (0..3)
  const float* relp = rel + ((size_t)h * NPIX + i0 + (iw << 4) + (g << 2)) * NPIX +
                      (jh << 9) + (ln << 2);
  f32x4 relA4[4], relB4[4];
#pragma unroll
  for (int v = 0; v < 4; ++v)
    relA4[v] = *reinterpret_cast<const f32x4*>(relp + (size_t)v * NPIX);

  f32x4 vzero = {0.f, 0.f, 0.f, 0.f};
  f32x4 accO[2] = {vzero, vzero};
  f32x4 l_lane = vzero;

  // V fragments of the PREVIOUS step, carried in named regs (deferred PV)
  bf16x8 vf00, vf01, vf10, vf11;

  u16* sPw = &sP[w][0];
  const float LOG2E = 1.4426950408889634f;

  // P-fragment LDS addresses (per-thread constant)
  const int paOff0 = ln * 64 + ((g ^ (ln & 7)) << 3);
  const int paOff1 = ln * 64 + (((4 | g) ^ (ln & 7)) << 3);
  // V-fragment LDS offsets (per-thread constant): d0 = ln, d1 = 16+ln
  const int vOff00 = ln * 64 + ((g ^ (ln & 7)) << 3);              // kc0,d0
  const int vOff01 = (16 + ln) * 64 + ((g ^ ((16 + ln) & 7)) << 3); // kc0,d1
  const int vOff10 = ln * 64 + (((4 | g) ^ (ln & 7)) << 3);         // kc1,d0
  const int vOff11 = (16 + ln) * 64 + (((4 | g) ^ ((16 + ln) & 7)) << 3);

  for (int s = 0; s < 8; ++s) {
    const int p = s & 1;
    __syncthreads();                        // K(s),V(s) staged in buf p
    if (s < 7) {
      STAGE(s + 1, p ^ 1);
#pragma unroll
      for (int v = 0; v < 4; ++v)
        relB4[v] = *reinterpret_cast<const f32x4*>(relp + (size_t)v * NPIX + ((s + 1) << 6));
    }

    // ---- deferred PV(s-1): P(s-1) in sPw (read precedes this step's writes
    // in program order; same-wave DS is in-order), V(s-1) in named regs ----
    if (s > 0) {
      __builtin_amdgcn_s_setprio(1);
      bf16x8 pa0 = *reinterpret_cast<const bf16x8*>(sPw + paOff0);
      accO[0] = __builtin_amdgcn_mfma_f32_16x16x32_bf16(pa0, vf00, accO[0], 0, 0, 0);
      accO[1] = __builtin_amdgcn_mfma_f32_16x16x32_bf16(pa0, vf01, accO[1], 0, 0, 0);
      bf16x8 pa1 = *reinterpret_cast<const bf16x8*>(sPw + paOff1);
      accO[0] = __builtin_amdgcn_mfma_f32_16x16x32_bf16(pa1, vf10, accO[0], 0, 0, 0);
      accO[1] = __builtin_amdgcn_mfma_f32_16x16x32_bf16(pa1, vf11, accO[1], 0, 0, 0);
      __builtin_amdgcn_s_setprio(0);
    }

    const u16* Kb = &sK[p][jh][0];
    const u16* Vb = &sV[p][jh][0];

    // ---- S' = Q'^T K: fragment jj covers cols j = 4*ln + jj ----
    f32x4 sfr[4];
    __builtin_amdgcn_s_setprio(1);
#pragma unroll
    for (int jj = 0; jj < 4; ++jj) {
      const int r  = (ln << 1) + (jj >> 1);
      const int ks = ((((jj & 1) << 2) | g) ^ (r & 7)) ^ ((r >> 3) & 1);
      bf16x8 kf = *reinterpret_cast<const bf16x8*>(Kb + r * 64 + ks * 8);
      sfr[jj] = __builtin_amdgcn_mfma_f32_16x16x32_bf16(qf, kf, vzero, 0, 0, 0);
    }
    __builtin_amdgcn_s_setprio(0);

    // ---- P = exp2(S' + rel*log2e); swizzled b64 write per row ----
#pragma unroll
    for (int v = 0; v < 4; ++v) {
      float p0 = EXP2(fmaf(relA4[v][0], LOG2E, sfr[0][v]));
      float p1 = EXP2(fmaf(relA4[v][1], LOG2E, sfr[1][v]));
      float p2 = EXP2(fmaf(relA4[v][2], LOG2E, sfr[2][v]));
      float p3 = EXP2(fmaf(relA4[v][3], LOG2E, sfr[3][v]));
      l_lane[v] += (p0 + p1) + (p2 + p3);
      bf16x4 pk;
      pk[0] = (__bf16)p0; pk[1] = (__bf16)p1; pk[2] = (__bf16)p2; pk[3] = (__bf16)p3;
      const int rw = (g << 2) + v;
      *reinterpret_cast<bf16x4*>(
          sPw + rw * 64 + ((((ln >> 1) ^ (rw & 7)) << 3) | ((ln & 1) << 2))) = pk;
    }

    // ---- load V(s) fragments into regs for next step's deferred PV ----
    vf00 = *reinterpret_cast<const bf16x8*>(Vb + vOff00);
    vf01 = *reinterpret_cast<const bf16x8*>(Vb + vOff01);
    vf10 = *reinterpret_cast<const bf16x8*>(Vb + vOff10);
    vf11 = *reinterpret_cast<const bf16x8*>(Vb + vOff11);

    if (s < 7) {
#pragma unroll
      for (int v = 0; v < 4; ++v) relA4[v] = relB4[v];
    }
  }
#undef STAGE

  // ---- final PV(7) ----
  {
    __builtin_amdgcn_s_setprio(1);
    bf16x8 pa0 = *reinterpret_cast<const bf16x8*>(sPw + paOff0);
    accO[0] = __builtin_amdgcn_mfma_f32_16x16x32_bf16(pa0, vf00, accO[0], 0, 0, 0);
    accO[1] = __builtin_amdgcn_mfma_f32_16x16x32_bf16(pa0, vf01, accO[1], 0, 0, 0);
    bf16x8 pa1 = *reinterpret_cast<const bf16x8*>(sPw + paOff1);
    accO[0] = __builtin_amdgcn_mfma_f32_16x16x32_bf16(pa1, vf10, accO[0], 0, 0, 0);
    accO[1] = __builtin_amdgcn_mfma_f32_16x16x32_bf16(pa1, vf11, accO[1], 0, 0, 0);
    __builtin_amdgcn_s_setprio(0);
  }

  // ---- merge the two j-halves, then finalize (jh==0 waves write out) ----
  __syncthreads();
  float* mrg = (float*)&sK[0][0][0];        // 12.3 KB scratch over sK space
  if (jh == 1) {
    float* mp = mrg + ((size_t)((iw << 6) + l)) * 12;
    *reinterpret_cast<f32x4*>(mp + 0) = accO[0];
    *reinterpret_cast<f32x4*>(mp + 4) = accO[1];
    *reinterpret_cast<f32x4*>(mp + 8) = l_lane;
  }
  __syncthreads();
  if (jh == 0) {
    const float* mp = mrg + ((size_t)((iw << 6) + l)) * 12;
    f32x4 o0 = accO[0] + *reinterpret_cast<const f32x4*>(mp + 0);
    f32x4 o1 = accO[1] + *reinterpret_cast<const f32x4*>(mp + 4);
    f32x4 lv = l_lane + *reinterpret_cast<const f32x4*>(mp + 8);
#pragma unroll
    for (int v = 0; v < 4; ++v) {
      float ls2 = lv[v];
      ls2 += __shfl_xor(ls2, 1);
      ls2 += __shfl_xor(ls2, 2);
      ls2 += __shfl_xor(ls2, 4);
      ls2 += __shfl_xor(ls2, 8);
      const float inv = 1.f / ls2;
      const size_t row = (size_t)b * NPIX + i0 + (iw << 4) + (g << 2) + v;
      aout[row * DATTN + (h << 5) + ln]      = f2bf(o0[v] * inv);
      aout[row * DATTN + (h << 5) + 16 + ln] = f2bf(o1[v] * inv);
    }
  }
}

// ---------------------------------------------------------------------------
// Proj GEMM (MFMA): out[b][o][n] = sum_k Wp[o,k] * A[b][n][k] + bias[o], f32 out.
// ---------------------------------------------------------------------------
__global__ __launch_bounds__(256) void gemm_proj_mfma(const u16* __restrict__ wp,
                                                      const u16* __restrict__ at,
                                                      const float* __restrict__ bias,
                                                      float* __restrict__ out) {
  __shared__ __align__(16) u16 sA[64 * 64];
  __shared__ __align__(16) u16 sB[128 * 64];
  const int t  = threadIdx.x;
  const int w  = t >> 6, l = t & 63, g = l >> 4, ln = l & 15;
  const int n0 = blockIdx.x * 128;
  const int o0 = blockIdx.y * 64;
  const int b  = blockIdx.z;
  const int wm = w >> 1, wn = w & 1;

  const u16* wbase = wp + (size_t)o0 * DATTN;
  const u16* abase = at + ((size_t)b * NPIX + n0) * DATTN;

  f32x4 acc[2][4];
#pragma unroll
  for (int mi = 0; mi < 2; ++mi)
#pragma unroll
    for (int ni = 0; ni < 4; ++ni) acc[mi][ni] = {0.f, 0.f, 0.f, 0.f};

  for (int k0 = 0; k0 < DATTN; k0 += 64) {
#pragma unroll
    for (int i = 0; i < 2; ++i) {
      int chunk = i * 256 + (w << 6) + l;
      gl_lds16(wbase + ((size_t)(chunk >> 3)) * DATTN + k0 + ((chunk & 7) << 3),
               (char*)sA + i * 4096 + (w << 10));
    }
#pragma unroll
    for (int i = 0; i < 4; ++i) {
      int chunk = i * 256 + (w << 6) + l;
      gl_lds16(abase + ((size_t)(chunk >> 3)) * DATTN + k0 + ((chunk & 7) << 3),
               (char*)sB + i * 4096 + (w << 10));
    }
    __syncthreads();
#pragma unroll
    for (int kk = 0; kk < 64; kk += 32) {
      bf16x8 af[2], bfr[4];
#pragma unroll
      for (int mi = 0; mi < 2; ++mi)
        af[mi] = *reinterpret_cast<const bf16x8*>(&sA[((wm << 5) + (mi << 4) + ln) * 64 + kk + (g << 3)]);
#pragma unroll
      for (int ni = 0; ni < 4; ++ni)
        bfr[ni] = *reinterpret_cast<const bf16x8*>(&sB[((wn << 6) + (ni << 4) + ln) * 64 + kk + (g << 3)]);
#pragma unroll
      for (int mi = 0; mi < 2; ++mi)
#pragma unroll
        for (int ni = 0; ni < 4; ++ni)
          acc[mi][ni] = __builtin_amdgcn_mfma_f32_16x16x32_bf16(af[mi], bfr[ni], acc[mi][ni], 0, 0, 0);
    }
    __syncthreads();
  }

#pragma unroll
  for (int mi = 0; mi < 2; ++mi) {
    const int o = o0 + (wm << 5) + (mi << 4) + (g << 2);
    const float b0 = bias[o], b1 = bias[o + 1], b2 = bias[o + 2], b3 = bias[o + 3];
#pragma unroll
    for (int ni = 0; ni < 4; ++ni) {
      const int n = n0 + (wn << 6) + (ni << 4) + ln;
      float* op = &out[((size_t)b * DATTN + o) * NPIX + n];
      op[0]        = acc[mi][ni][0] + b0;
      op[NPIX]     = acc[mi][ni][1] + b1;
      op[2 * NPIX] = acc[mi][ni][2] + b2;
      op[3 * NPIX] = acc[mi][ni][3] + b3;
    }
  }
}

extern "C" void kernel_launch(void* const* d_in, const int* in_sizes, int n_in,
                              void* d_out, int out_size, void* d_ws, size_t ws_size,
                              hipStream_t stream) {
  (void)in_sizes; (void)n_in; (void)out_size; (void)ws_size;
  const float* x      = (const float*)d_in[0];
  const float* w_qkv  = (const float*)d_in[1];
  const float* b_qkv  = (const float*)d_in[2];
  const float* w_proj = (const float*)d_in[3];
  const float* b_proj = (const float*)d_in[4];
  const float* rel    = (const float*)d_in[5];
  float* out = (float*)d_out;

  u16* xt    = (u16*)d_ws;                                   // 4 MB
  u16* wq_bf = xt + (size_t)BATCH * NPIX * CIN;              // 1.5 MB
  u16* wp_bf = wq_bf + (size_t)O_QKV * CIN;                  // 0.5 MB
  u16* qt    = wp_bf + (size_t)DATTN * DATTN;                // 4 MB
  u16* kt    = qt + (size_t)BATCH * HEADS * NPIX * DH;       // 4 MB
  u16* vt    = kt + (size_t)BATCH * HEADS * NPIX * DH;       // 4 MB
  u16* aout  = vt + (size_t)BATCH * HEADS * NPIX * DH;       // 4 MB

  prep_w<<<1024, 256, 0, stream>>>(w_qkv, w_proj, wq_bf, wp_bf);
  prep_x<<<dim3(NPIX / 64, CIN / 64, BATCH), 256, 0, stream>>>(x, xt);
  gemm_qkv_mfma<<<dim3(NPIX / 128, HEADS, BATCH), 256, 0, stream>>>(wq_bf, xt, b_qkv, qt, kt, vt);
  attn_mfma<<<1024, 512, 0, stream>>>(qt, kt, vt, rel, aout);
  gemm_proj_mfma<<<dim3(NPIX / 128, DATTN / 64, BATCH), 256, 0, stream>>>(wp_bf, aout, b_proj, out);
}

// Round 13
// 63.122 us; speedup vs baseline: 1.9315x; 1.0001x over previous
//
#include <hip/hip_runtime.h>
#include <cstdint>
#include <cstddef>

#define BATCH 4
#define CIN   512
#define NPIX  1024
#define HEADS 16
#define DH    32
#define DATTN 512
#define O_QKV 1536

typedef unsigned short u16;
typedef __bf16 bf16x4 __attribute__((ext_vector_type(4)));
typedef __bf16 bf16x8 __attribute__((ext_vector_type(8)));
typedef float  f32x4  __attribute__((ext_vector_type(4)));

typedef const __attribute__((address_space(1))) void g1_t;
typedef __attribute__((address_space(3))) void l3_t;

#if defined(__has_builtin)
#if __has_builtin(__builtin_amdgcn_exp2f)
#define EXP2(x) __builtin_amdgcn_exp2f(x)
#endif
#endif
#ifndef EXP2
#define EXP2(x) __expf((x) * 0.6931471805599453f)
#endif

__device__ __forceinline__ u16 f2bf(float f) {
  unsigned u = __float_as_uint(f);
  u += 0x7fffu + ((u >> 16) & 1u);
  return (u16)(u >> 16);
}

// async global->LDS, 16B per lane; lp must be wave-uniform (HW: base + lane*16)
__device__ __forceinline__ void gl_lds16(const void* gp, void* lp) {
  __builtin_amdgcn_global_load_lds((g1_t*)gp, (l3_t*)lp, 16, 0, 0);
}

// ---------------------------------------------------------------------------
// prep_w: convert w_qkv [1536][512] and w_proj [512][512] f32 -> bf16.
// ---------------------------------------------------------------------------
__global__ __launch_bounds__(256) void prep_w(const float* __restrict__ w1,
                                              const float* __restrict__ w2,
                                              u16* __restrict__ o1,
                                              u16* __restrict__ o2) {
  const int idx = blockIdx.x * 256 + threadIdx.x;   // float4 index
  const int n1 = (O_QKV * CIN) >> 2;                // 196608
  float4 v = (idx < n1) ? reinterpret_cast<const float4*>(w1)[idx]
                        : reinterpret_cast<const float4*>(w2)[idx - n1];
  uint2 pk = make_uint2((unsigned)f2bf(v.x) | ((unsigned)f2bf(v.y) << 16),
                        (unsigned)f2bf(v.z) | ((unsigned)f2bf(v.w) << 16));
  if (idx < n1) reinterpret_cast<uint2*>(o1)[idx] = pk;
  else          reinterpret_cast<uint2*>(o2)[idx - n1] = pk;
}

// ---------------------------------------------------------------------------
// prep_x: x [B][C][N] f32 -> xt [B][N][C] bf16 (tiled 64x64 LDS transpose)
// ---------------------------------------------------------------------------
__global__ __launch_bounds__(256) void prep_x(const float* __restrict__ x,
                                              u16* __restrict__ xt) {
  __shared__ float sT[64][65];
  const int t  = threadIdx.x;
  const int n0 = blockIdx.x * 64;
  const int c0 = blockIdx.y * 64;
  const int b  = blockIdx.z;
  const float* xb = x + ((size_t)b * CIN + c0) * NPIX + n0;
#pragma unroll
  for (int i = 0; i < 4; ++i) {
    int r   = i * 16 + (t >> 4);
    int col = (t & 15) << 2;
    float4 v = *reinterpret_cast<const float4*>(&xb[(size_t)r * NPIX + col]);
    sT[r][col + 0] = v.x; sT[r][col + 1] = v.y;
    sT[r][col + 2] = v.z; sT[r][col + 3] = v.w;
  }
  __syncthreads();
#pragma unroll
  for (int i = 0; i < 2; ++i) {
    int nl = t >> 2;
    int ch = (t & 3) + (i << 2);
    u16 tmp[8];
#pragma unroll
    for (int e = 0; e < 8; ++e) tmp[e] = f2bf(sT[(ch << 3) + e][nl]);
    *reinterpret_cast<uint4*>(&xt[((size_t)b * NPIX + n0 + nl) * CIN + c0 + (ch << 3)]) =
        *reinterpret_cast<uint4*>(tmp);
  }
}

// ---------------------------------------------------------------------------
// QKV GEMM (MFMA): M-tile=96 (one head), N-tile=128, BK=64, 4 waves.
// Epilogue: +bias, bf16; q PRE-SCALED by scale*log2e (attn uses exp2 domain).
// qt/kt [b][h][n][32], vt [b][h][d][n].
// ---------------------------------------------------------------------------
__global__ __launch_bounds__(256) void gemm_qkv_mfma(const u16* __restrict__ wq,
                                                     const u16* __restrict__ xt,
                                                     const float* __restrict__ bias,
                                                     u16* __restrict__ qt,
                                                     u16* __restrict__ kt,
                                                     u16* __restrict__ vt) {
  __shared__ __align__(16) u16 sA[96 * 64];
  __shared__ __align__(16) u16 sB[128 * 64];
  const int t  = threadIdx.x;
  const int w  = t >> 6, l = t & 63, g = l >> 4, ln = l & 15;
  const int n0 = blockIdx.x * 128;
  const int h  = blockIdx.y;
  const int b  = blockIdx.z;
  const int wm = w >> 1, wn = w & 1;

  const u16* wbase = wq + (size_t)h * 96 * CIN;
  const u16* xbase = xt + ((size_t)b * NPIX + n0) * CIN;

  f32x4 acc[3][4];
#pragma unroll
  for (int mi = 0; mi < 3; ++mi)
#pragma unroll
    for (int ni = 0; ni < 4; ++ni) acc[mi][ni] = {0.f, 0.f, 0.f, 0.f};

  for (int k0 = 0; k0 < CIN; k0 += 64) {
#pragma unroll
    for (int i = 0; i < 3; ++i) {
      int chunk = i * 256 + (w << 6) + l;
      gl_lds16(wbase + ((size_t)(chunk >> 3)) * CIN + k0 + ((chunk & 7) << 3),
               (char*)sA + i * 4096 + (w << 10));
    }
#pragma unroll
    for (int i = 0; i < 4; ++i) {
      int chunk = i * 256 + (w << 6) + l;
      gl_lds16(xbase + ((size_t)(chunk >> 3)) * CIN + k0 + ((chunk & 7) << 3),
               (char*)sB + i * 4096 + (w << 10));
    }
    __syncthreads();
#pragma unroll
    for (int kk = 0; kk < 64; kk += 32) {
      bf16x8 af[3], bfr[4];
#pragma unroll
      for (int mi = 0; mi < 3; ++mi)
        af[mi] = *reinterpret_cast<const bf16x8*>(&sA[(48 * wm + 16 * mi + ln) * 64 + kk + (g << 3)]);
#pragma unroll
      for (int ni = 0; ni < 4; ++ni)
        bfr[ni] = *reinterpret_cast<const bf16x8*>(&sB[((wn << 6) + (ni << 4) + ln) * 64 + kk + (g << 3)]);
#pragma unroll
      for (int mi = 0; mi < 3; ++mi)
#pragma unroll
        for (int ni = 0; ni < 4; ++ni)
          acc[mi][ni] = __builtin_amdgcn_mfma_f32_16x16x32_bf16(af[mi], bfr[ni], acc[mi][ni], 0, 0, 0);
    }
    __syncthreads();
  }

  const float QSC = 0.17677669529663687f * 1.4426950408889634f;  // scale*log2e
  const float* bh = bias + h * 96;
#pragma unroll
  for (int mi = 0; mi < 3; ++mi) {
    const int sec = 48 * wm + 16 * mi;
    const int rb  = sec + (g << 2);
    const float b0 = bh[rb + 0], b1 = bh[rb + 1], b2 = bh[rb + 2], b3 = bh[rb + 3];
#pragma unroll
    for (int ni = 0; ni < 4; ++ni) {
      const int n = n0 + (wn << 6) + (ni << 4) + ln;
      f32x4 a = acc[mi][ni];
      float v0 = a[0] + b0, v1 = a[1] + b1, v2 = a[2] + b2, v3 = a[3] + b3;
      if (sec < 32) { v0 *= QSC; v1 *= QSC; v2 *= QSC; v3 *= QSC; }
      u16 e0 = f2bf(v0), e1 = f2bf(v1), e2 = f2bf(v2), e3 = f2bf(v3);
      if (sec < 32) {
        const int d = sec + (g << 2);
        uint2 pk = make_uint2((unsigned)e0 | ((unsigned)e1 << 16),
                              (unsigned)e2 | ((unsigned)e3 << 16));
        *reinterpret_cast<uint2*>(&qt[(((size_t)(b * HEADS + h)) * NPIX + n) * DH + d]) = pk;
      } else if (sec < 64) {
        const int d = sec - 32 + (g << 2);
        uint2 pk = make_uint2((unsigned)e0 | ((unsigned)e1 << 16),
                              (unsigned)e2 | ((unsigned)e3 << 16));
        *reinterpret_cast<uint2*>(&kt[(((size_t)(b * HEADS + h)) * NPIX + n) * DH + d]) = pk;
      } else {
        const int d = sec - 64 + (g << 2);
        u16* vp = &vt[(((size_t)(b * HEADS + h)) * DH + d) * NPIX + n];
        vp[0] = e0; vp[NPIX] = e1; vp[2 * NPIX] = e2; vp[3 * NPIX] = e3;
      }
    }
  }
}

// ---------------------------------------------------------------------------
// MFMA flash attention v13 = r12 (deferred PV) + COUNTED-VMCNT BARRIERS (T4).
// In-loop barrier = s_waitcnt vmcnt(4) + raw s_barrier + sched_barrier(0):
// the 2 oldest outstanding VMEM ops are this step's K/V global_load_lds (must
// land); the 4 newest are next step's rel loads (stay in flight; compiler
// inserts its own wait before their use). No vmcnt(0) drain in the main loop
// -> staging overlaps compute across barriers (T4; r6's attempt was
// confounded by (512,6) spill + broken rel decode, both fixed here).
// Safety: every wave's ds_read results are lgkm-waited before MFMA use (all
// pre-barrier), so re-staging the other buffer after a drain-free barrier is
// race-free; sP is wave-private (same-wave DS in-order).
// Rest identical to r12: 512 thr, 8 waves = 4 iw x 2 jh; 8 j-steps; LDS 48KB;
// (512,4); grid 1024 XCD-decode; deferred PV; LDS merge epilogue.
// ---------------------------------------------------------------------------
__global__ __launch_bounds__(512, 4) void attn_mfma(const u16* __restrict__ qt,
                                                    const u16* __restrict__ kt,
                                                    const u16* __restrict__ vt,
                                                    const float* __restrict__ rel,
                                                    u16* __restrict__ aout) {
  __shared__ __align__(16) u16 sK[2][2][2048];   // [buf][jh][32r][8slot][8] 16KB
  __shared__ __align__(16) u16 sV[2][2][2048];   // [buf][jh][32d][8slot][8] 16KB
  __shared__ __align__(16) u16 sP[8][1024];      // per-wave [16][8slot][8]  16KB

  const int t  = threadIdx.x;
  const int w  = t >> 6, l = t & 63, g = l >> 4, ln = l & 15;
  const int bid = blockIdx.x;
  const int xcd = bid & 7, sl = bid >> 3;   // sl 0..127
  const int b   = sl & 3;
  const int i0  = ((sl >> 2) & 15) << 6;
  const int h   = (xcd << 1) | (sl >> 6);
  const int iw  = w & 3;                    // i-segment (16 rows)
  const int jh  = w >> 2;                   // j-half (512 cols)

  const size_t bh = (size_t)(b * HEADS + h);

  // staging (per-thread constant): wave w stages quarter iw of j-half (w>>2).
  const int lr = l >> 3, ls = l & 7;
  const int sjh = w >> 2;
  const int kcl = ls ^ lr ^ (iw & 1);                 // K logical chunk
  const int kj  = (iw << 4) + (lr << 1) + (kcl >> 2); // j within half
  const u16* ksrc = kt + (bh * NPIX + (sjh << 9) + kj) * DH + ((kcl & 3) << 3);
  const int vcl = ls ^ lr;                            // V logical chunk
  const int vd  = (iw << 3) + lr;                     // d row
  const u16* vsrc = vt + (bh * DH + vd) * NPIX + (sjh << 9) + (vcl << 3);
  char* kdst = (char*)&sK[0][sjh][0] + (iw << 10);
  char* vdst = (char*)&sV[0][sjh][0] + (iw << 10);

#define STAGE(s_, p_) do {                                          \
    gl_lds16(ksrc + (size_t)(s_) * 2048, kdst + (p_) * 8192);       \
    gl_lds16(vsrc + (size_t)(s_) * 64,   vdst + (p_) * 8192);       \
  } while (0)

  STAGE(0, 0);

  // Q fragment (pre-scaled by scale*log2e): lane -> row i0+16*iw+ln, k=8g..+8
  bf16x8 qf = *reinterpret_cast<const bf16x8*>(
      qt + (bh * NPIX + i0 + (iw << 4) + ln) * DH + (g << 3));

  // rel: rows i0+16iw+4g+v, cols jh*512 + s*64 + 4ln + (0..3)
  const float* relp = rel + ((size_t)h * NPIX + i0 + (iw << 4) + (g << 2)) * NPIX +
                      (jh << 9) + (ln << 2);
  f32x4 relA4[4], relB4[4];
#pragma unroll
  for (int v = 0; v < 4; ++v)
    relA4[v] = *reinterpret_cast<const f32x4*>(relp + (size_t)v * NPIX);

  f32x4 vzero = {0.f, 0.f, 0.f, 0.f};
  f32x4 accO[2] = {vzero, vzero};
  f32x4 l_lane = vzero;

  // V fragments of the PREVIOUS step, carried in named regs (deferred PV)
  bf16x8 vf00, vf01, vf10, vf11;

  u16* sPw = &sP[w][0];
  const float LOG2E = 1.4426950408889634f;

  // P-fragment LDS addresses (per-thread constant)
  const int paOff0 = ln * 64 + ((g ^ (ln & 7)) << 3);
  const int paOff1 = ln * 64 + (((4 | g) ^ (ln & 7)) << 3);
  // V-fragment LDS offsets (per-thread constant): d0 = ln, d1 = 16+ln
  const int vOff00 = ln * 64 + ((g ^ (ln & 7)) << 3);              // kc0,d0
  const int vOff01 = (16 + ln) * 64 + ((g ^ ((16 + ln) & 7)) << 3); // kc0,d1
  const int vOff10 = ln * 64 + (((4 | g) ^ (ln & 7)) << 3);         // kc1,d0
  const int vOff11 = (16 + ln) * 64 + (((4 | g) ^ ((16 + ln) & 7)) << 3);

  for (int s = 0; s < 8; ++s) {
    const int p = s & 1;
    // ---- T4 counted barrier: K/V gl_lds for buf p are the 2 oldest VMEM
    // ops; the 4 newest are rel prefetches (allowed to stay in flight).
    asm volatile("s_waitcnt vmcnt(4)" ::: "memory");
    __builtin_amdgcn_s_barrier();
    __builtin_amdgcn_sched_barrier(0);

    if (s < 7) {
      STAGE(s + 1, p ^ 1);
#pragma unroll
      for (int v = 0; v < 4; ++v)
        relB4[v] = *reinterpret_cast<const f32x4*>(relp + (size_t)v * NPIX + ((s + 1) << 6));
    }

    // ---- deferred PV(s-1): P(s-1) in sPw (read precedes this step's writes
    // in program order; same-wave DS is in-order), V(s-1) in named regs ----
    if (s > 0) {
      __builtin_amdgcn_s_setprio(1);
      bf16x8 pa0 = *reinterpret_cast<const bf16x8*>(sPw + paOff0);
      accO[0] = __builtin_amdgcn_mfma_f32_16x16x32_bf16(pa0, vf00, accO[0], 0, 0, 0);
      accO[1] = __builtin_amdgcn_mfma_f32_16x16x32_bf16(pa0, vf01, accO[1], 0, 0, 0);
      bf16x8 pa1 = *reinterpret_cast<const bf16x8*>(sPw + paOff1);
      accO[0] = __builtin_amdgcn_mfma_f32_16x16x32_bf16(pa1, vf10, accO[0], 0, 0, 0);
      accO[1] = __builtin_amdgcn_mfma_f32_16x16x32_bf16(pa1, vf11, accO[1], 0, 0, 0);
      __builtin_amdgcn_s_setprio(0);
    }

    const u16* Kb = &sK[p][jh][0];
    const u16* Vb = &sV[p][jh][0];

    // ---- S' = Q'^T K: fragment jj covers cols j = 4*ln + jj ----
    f32x4 sfr[4];
    __builtin_amdgcn_s_setprio(1);
#pragma unroll
    for (int jj = 0; jj < 4; ++jj) {
      const int r  = (ln << 1) + (jj >> 1);
      const int ks = ((((jj & 1) << 2) | g) ^ (r & 7)) ^ ((r >> 3) & 1);
      bf16x8 kf = *reinterpret_cast<const bf16x8*>(Kb + r * 64 + ks * 8);
      sfr[jj] = __builtin_amdgcn_mfma_f32_16x16x32_bf16(qf, kf, vzero, 0, 0, 0);
    }
    __builtin_amdgcn_s_setprio(0);

    // ---- P = exp2(S' + rel*log2e); swizzled b64 write per row ----
#pragma unroll
    for (int v = 0; v < 4; ++v) {
      float p0 = EXP2(fmaf(relA4[v][0], LOG2E, sfr[0][v]));
      float p1 = EXP2(fmaf(relA4[v][1], LOG2E, sfr[1][v]));
      float p2 = EXP2(fmaf(relA4[v][2], LOG2E, sfr[2][v]));
      float p3 = EXP2(fmaf(relA4[v][3], LOG2E, sfr[3][v]));
      l_lane[v] += (p0 + p1) + (p2 + p3);
      bf16x4 pk;
      pk[0] = (__bf16)p0; pk[1] = (__bf16)p1; pk[2] = (__bf16)p2; pk[3] = (__bf16)p3;
      const int rw = (g << 2) + v;
      *reinterpret_cast<bf16x4*>(
          sPw + rw * 64 + ((((ln >> 1) ^ (rw & 7)) << 3) | ((ln & 1) << 2))) = pk;
    }

    // ---- load V(s) fragments into regs for next step's deferred PV ----
    vf00 = *reinterpret_cast<const bf16x8*>(Vb + vOff00);
    vf01 = *reinterpret_cast<const bf16x8*>(Vb + vOff01);
    vf10 = *reinterpret_cast<const bf16x8*>(Vb + vOff10);
    vf11 = *reinterpret_cast<const bf16x8*>(Vb + vOff11);

    if (s < 7) {
#pragma unroll
      for (int v = 0; v < 4; ++v) relA4[v] = relB4[v];
    }
  }
#undef STAGE

  // ---- final PV(7) ----
  {
    __builtin_amdgcn_s_setprio(1);
    bf16x8 pa0 = *reinterpret_cast<const bf16x8*>(sPw + paOff0);
    accO[0] = __builtin_amdgcn_mfma_f32_16x16x32_bf16(pa0, vf00, accO[0], 0, 0, 0);
    accO[1] = __builtin_amdgcn_mfma_f32_16x16x32_bf16(pa0, vf01, accO[1], 0, 0, 0);
    bf16x8 pa1 = *reinterpret_cast<const bf16x8*>(sPw + paOff1);
    accO[0] = __builtin_amdgcn_mfma_f32_16x16x32_bf16(pa1, vf10, accO[0], 0, 0, 0);
    accO[1] = __builtin_amdgcn_mfma_f32_16x16x32_bf16(pa1, vf11, accO[1], 0, 0, 0);
    __builtin_amdgcn_s_setprio(0);
  }

  // ---- merge the two j-halves, then finalize (jh==0 waves write out) ----
  __syncthreads();
  float* mrg = (float*)&sK[0][0][0];        // 12.3 KB scratch over sK space
  if (jh == 1) {
    float* mp = mrg + ((size_t)((iw << 6) + l)) * 12;
    *reinterpret_cast<f32x4*>(mp + 0) = accO[0];
    *reinterpret_cast<f32x4*>(mp + 4) = accO[1];
    *reinterpret_cast<f32x4*>(mp + 8) = l_lane;
  }
  __syncthreads();
  if (jh == 0) {
    const float* mp = mrg + ((size_t)((iw << 6) + l)) * 12;
    f32x4 o0 = accO[0] + *reinterpret_cast<const f32x4*>(mp + 0);
    f32x4 o1 = accO[1] + *reinterpret_cast<const f32x4*>(mp + 4);
    f32x4 lv = l_lane + *reinterpret_cast<const f32x4*>(mp + 8);
#pragma unroll
    for (int v = 0; v < 4; ++v) {
      float ls2 = lv[v];
      ls2 += __shfl_xor(ls2, 1);
      ls2 += __shfl_xor(ls2, 2);
      ls2 += __shfl_xor(ls2, 4);
      ls2 += __shfl_xor(ls2, 8);
      const float inv = 1.f / ls2;
      const size_t row = (size_t)b * NPIX + i0 + (iw << 4) + (g << 2) + v;
      aout[row * DATTN + (h << 5) + ln]      = f2bf(o0[v] * inv);
      aout[row * DATTN + (h << 5) + 16 + ln] = f2bf(o1[v] * inv);
    }
  }
}

// ---------------------------------------------------------------------------
// Proj GEMM (MFMA): out[b][o][n] = sum_k Wp[o,k] * A[b][n][k] + bias[o], f32 out.
// ---------------------------------------------------------------------------
__global__ __launch_bounds__(256) void gemm_proj_mfma(const u16* __restrict__ wp,
                                                      const u16* __restrict__ at,
                                                      const float* __restrict__ bias,
                                                      float* __restrict__ out) {
  __shared__ __align__(16) u16 sA[64 * 64];
  __shared__ __align__(16) u16 sB[128 * 64];
  const int t  = threadIdx.x;
  const int w  = t >> 6, l = t & 63, g = l >> 4, ln = l & 15;
  const int n0 = blockIdx.x * 128;
  const int o0 = blockIdx.y * 64;
  const int b  = blockIdx.z;
  const int wm = w >> 1, wn = w & 1;

  const u16* wbase = wp + (size_t)o0 * DATTN;
  const u16* abase = at + ((size_t)b * NPIX + n0) * DATTN;

  f32x4 acc[2][4];
#pragma unroll
  for (int mi = 0; mi < 2; ++mi)
#pragma unroll
    for (int ni = 0; ni < 4; ++ni) acc[mi][ni] = {0.f, 0.f, 0.f, 0.f};

  for (int k0 = 0; k0 < DATTN; k0 += 64) {
#pragma unroll
    for (int i = 0; i < 2; ++i) {
      int chunk = i * 256 + (w << 6) + l;
      gl_lds16(wbase + ((size_t)(chunk >> 3)) * DATTN + k0 + ((chunk & 7) << 3),
               (char*)sA + i * 4096 + (w << 10));
    }
#pragma unroll
    for (int i = 0; i < 4; ++i) {
      int chunk = i * 256 + (w << 6) + l;
      gl_lds16(abase + ((size_t)(chunk >> 3)) * DATTN + k0 + ((chunk & 7) << 3),
               (char*)sB + i * 4096 + (w << 10));
    }
    __syncthreads();
#pragma unroll
    for (int kk = 0; kk < 64; kk += 32) {
      bf16x8 af[2], bfr[4];
#pragma unroll
      for (int mi = 0; mi < 2; ++mi)
        af[mi] = *reinterpret_cast<const bf16x8*>(&sA[((wm << 5) + (mi << 4) + ln) * 64 + kk + (g << 3)]);
#pragma unroll
      for (int ni = 0; ni < 4; ++ni)
        bfr[ni] = *reinterpret_cast<const bf16x8*>(&sB[((wn << 6) + (ni << 4) + ln) * 64 + kk + (g << 3)]);
#pragma unroll
      for (int mi = 0; mi < 2; ++mi)
#pragma unroll
        for (int ni = 0; ni < 4; ++ni)
          acc[mi][ni] = __builtin_amdgcn_mfma_f32_16x16x32_bf16(af[mi], bfr[ni], acc[mi][ni], 0, 0, 0);
    }
    __syncthreads();
  }

#pragma unroll
  for (int mi = 0; mi < 2; ++mi) {
    const int o = o0 + (wm << 5) + (mi << 4) + (g << 2);
    const float b0 = bias[o], b1 = bias[o + 1], b2 = bias[o + 2], b3 = bias[o + 3];
#pragma unroll
    for (int ni = 0; ni < 4; ++ni) {
      const int n = n0 + (wn << 6) + (ni << 4) + ln;
      float* op = &out[((size_t)b * DATTN + o) * NPIX + n];
      op[0]        = acc[mi][ni][0] + b0;
      op[NPIX]     = acc[mi][ni][1] + b1;
      op[2 * NPIX] = acc[mi][ni][2] + b2;
      op[3 * NPIX] = acc[mi][ni][3] + b3;
    }
  }
}

extern "C" void kernel_launch(void* const* d_in, const int* in_sizes, int n_in,
                              void* d_out, int out_size, void* d_ws, size_t ws_size,
                              hipStream_t stream) {
  (void)in_sizes; (void)n_in; (void)out_size; (void)ws_size;
  const float* x      = (const float*)d_in[0];
  const float* w_qkv  = (const float*)d_in[1];
  const float* b_qkv  = (const float*)d_in[2];
  const float* w_proj = (const float*)d_in[3];
  const float* b_proj = (const float*)d_in[4];
  const float* rel    = (const float*)d_in[5];
  float* out = (float*)d_out;

  u16* xt    = (u16*)d_ws;                                   // 4 MB
  u16* wq_bf = xt + (size_t)BATCH * NPIX * CIN;              // 1.5 MB
  u16* wp_bf = wq_bf + (size_t)O_QKV * CIN;                  // 0.5 MB
  u16* qt    = wp_bf + (size_t)DATTN * DATTN;                // 4 MB
  u16* kt    = qt + (size_t)BATCH * HEADS * NPIX * DH;       // 4 MB
  u16* vt    = kt + (size_t)BATCH * HEADS * NPIX * DH;       // 4 MB
  u16* aout  = vt + (size_t)BATCH * HEADS * NPIX * DH;       // 4 MB

  prep_w<<<1024, 256, 0, stream>>>(w_qkv, w_proj, wq_bf, wp_bf);
  prep_x<<<dim3(NPIX / 64, CIN / 64, BATCH), 256, 0, stream>>>(x, xt);
  gemm_qkv_mfma<<<dim3(NPIX / 128, HEADS, BATCH), 256, 0, stream>>>(wq_bf, xt, b_qkv, qt, kt, vt);
  attn_mfma<<<1024, 512, 0, stream>>>(qt, kt, vt, rel, aout);
  gemm_proj_mfma<<<dim3(NPIX / 128, DATTN / 64, BATCH), 256, 0, stream>>>(wp_bf, aout, b_proj, out);
}